// Round 2
// baseline (883.349 us; speedup 1.0000x reference)
//
#include <hip/hip_runtime.h>
#include <hip/hip_bf16.h>
#include <cstdint>
#include <cstddef>

using bf16 = __hip_bfloat16;
#define DEVFN static __device__ __forceinline__

constexpr int B = 4, V = 6, P = 200, C = 256, HH = 8, Dh = 32, NLEV = 4, NPTS = 4, FFN = 1024;
constexpr int L = 7441;
constexpr int BV = B * V, BP = B * P, BVP = B * V * P, BVL = B * V * L;
constexpr float IMG_W = 800.f, IMG_H = 448.f;

__constant__ int cLH[4] = {56, 28, 14, 7};
__constant__ int cLW[4] = {100, 50, 25, 13};
__constant__ int cLS[4] = {0, 5600, 7000, 7350};

// ---- workspace layout (offsets in floats) ----
constexpr size_t IRT   = 0;
constexpr size_t CAMT  = IRT + (size_t)BV * 16;
constexpr size_t MFLAG = CAMT + (size_t)BV * 3;
constexpr size_t Xo    = MFLAG + BV;
constexpr size_t QPOSo = Xo + (size_t)BP * C;
constexpr size_t Qo    = QPOSo + (size_t)BP * C;
constexpr size_t Ko    = Qo + (size_t)BP * C;
constexpr size_t VVo   = Ko + (size_t)BP * C;
constexpr size_t LOGo  = VVo + (size_t)BP * C;
constexpr size_t SAo   = LOGo + (size_t)B * HH * P * P;
constexpr size_t X1o   = SAo + (size_t)BVP * C;
constexpr size_t REFo  = X1o + (size_t)BVP * C;
constexpr size_t OFFo  = REFo + (size_t)BVP * 2;
constexpr size_t AWo   = OFFo + (size_t)BVP * 256;
constexpr size_t OUTSo = AWo + (size_t)BVP * 128;
constexpr size_t X2o   = OUTSo + (size_t)BVP * C;
constexpr size_t X3o   = X2o + (size_t)BVP * C;
constexpr size_t FUSEDo= X3o + (size_t)BVP * C;
constexpr size_t WS_FLOATS = FUSEDo + (size_t)BP * C;
constexpr size_t VALS_BYTE_OFF = ((WS_FLOATS * 4 + 255) / 256) * 256;
constexpr size_t VALS_ELEMS = (size_t)BVL * C;   // bf16

// bf16 weight region (elements, after vals)
constexpr size_t KW2T_O  = 0;
constexpr size_t DVWT_O  = 65536;
constexpr size_t WOT_O   = 131072;
constexpr size_t DOUTT_O = 196608;
constexpr size_t OAWT_O  = 262144;            // 384x256
constexpr size_t QKVT_O  = 360448;            // 768x512
constexpr size_t W1T_O   = 753664;            // 1024x256
constexpr size_t W2T_O   = 1015808;           // 256x1024
constexpr size_t HIDB_O  = 1277952;           // 4800x1024 bf16

// ---- output layout (elements, f32) ----
constexpr size_t O0 = 0;
constexpr size_t O1 = O0 + (size_t)B * C * P;
constexpr size_t O2 = O1 + (size_t)B * P * 3;
constexpr size_t O3 = O2 + (size_t)B * P * 2;
constexpr size_t O4 = O3 + (size_t)B * 2 * P;

DEVFN float tof(bf16 x) { return __bfloat162float(x); }
DEVFN bf16  tobf(float x) { return __float2bfloat16(x); }

typedef __attribute__((ext_vector_type(8))) short short8;
typedef __attribute__((ext_vector_type(4))) float floatx4;

DEVFN float blockReduceSum(float v, float* red) {
    int j = threadIdx.x;
    __syncthreads();
    red[j] = v; __syncthreads();
    for (int s = 128; s > 0; s >>= 1) { if (j < s) red[j] += red[j + s]; __syncthreads(); }
    return red[0];
}

DEVFN float dotK(const float* __restrict__ s, const float* __restrict__ W, int j, int N, int K) {
    float acc = 0.f;
    for (int k = 0; k < K; k += 4) {
        float4 h = *(const float4*)(s + k);
        acc += h.x * W[(size_t)(k + 0) * N + j];
        acc += h.y * W[(size_t)(k + 1) * N + j];
        acc += h.z * W[(size_t)(k + 2) * N + j];
        acc += h.w * W[(size_t)(k + 3) * N + j];
    }
    return acc;
}

// ---------------- setup ----------------
__global__ __launch_bounds__(64) void k_setup(const float* rt, const float* l2cr, const float* l2ct,
                                              const int* maskin, float* ws) {
    int t = threadIdx.x;
    if (t >= BV) return;
    float m[16], inv[16];
    for (int i = 0; i < 16; i++) m[i] = rt[t * 16 + i];
    inv[0]  =  m[5]*m[10]*m[15] - m[5]*m[11]*m[14] - m[9]*m[6]*m[15] + m[9]*m[7]*m[14] + m[13]*m[6]*m[11] - m[13]*m[7]*m[10];
    inv[4]  = -m[4]*m[10]*m[15] + m[4]*m[11]*m[14] + m[8]*m[6]*m[15] - m[8]*m[7]*m[14] - m[12]*m[6]*m[11] + m[12]*m[7]*m[10];
    inv[8]  =  m[4]*m[9]*m[15]  - m[4]*m[11]*m[13] - m[8]*m[5]*m[15] + m[8]*m[7]*m[13] + m[12]*m[5]*m[11] - m[12]*m[7]*m[9];
    inv[12] = -m[4]*m[9]*m[14]  + m[4]*m[10]*m[13] + m[8]*m[5]*m[14] - m[8]*m[6]*m[13] - m[12]*m[5]*m[10] + m[12]*m[6]*m[9];
    inv[1]  = -m[1]*m[10]*m[15] + m[1]*m[11]*m[14] + m[9]*m[2]*m[15] - m[9]*m[3]*m[14] - m[13]*m[2]*m[11] + m[13]*m[3]*m[10];
    inv[5]  =  m[0]*m[10]*m[15] - m[0]*m[11]*m[14] - m[8]*m[2]*m[15] + m[8]*m[3]*m[14] + m[12]*m[2]*m[11] - m[12]*m[3]*m[10];
    inv[9]  = -m[0]*m[9]*m[15]  + m[0]*m[11]*m[13] + m[8]*m[1]*m[15] - m[8]*m[3]*m[13] - m[12]*m[1]*m[11] + m[12]*m[3]*m[9];
    inv[13] =  m[0]*m[9]*m[14]  - m[0]*m[10]*m[13] - m[8]*m[1]*m[14] + m[8]*m[2]*m[13] + m[12]*m[1]*m[10] - m[12]*m[2]*m[9];
    inv[2]  =  m[1]*m[6]*m[15]  - m[1]*m[7]*m[14]  - m[5]*m[2]*m[15] + m[5]*m[3]*m[14] + m[13]*m[2]*m[7]  - m[13]*m[3]*m[6];
    inv[6]  = -m[0]*m[6]*m[15]  + m[0]*m[7]*m[14]  + m[4]*m[2]*m[15] - m[4]*m[3]*m[14] - m[12]*m[2]*m[7]  + m[12]*m[3]*m[6];
    inv[10] =  m[0]*m[5]*m[15]  - m[0]*m[7]*m[13]  - m[4]*m[1]*m[15] + m[4]*m[3]*m[13] + m[12]*m[1]*m[7]  - m[12]*m[3]*m[5];
    inv[14] = -m[0]*m[5]*m[14]  + m[0]*m[6]*m[13]  + m[4]*m[1]*m[14] - m[4]*m[2]*m[13] - m[12]*m[1]*m[6]  + m[12]*m[2]*m[5];
    inv[3]  = -m[1]*m[6]*m[11]  + m[1]*m[7]*m[10]  + m[5]*m[2]*m[11] - m[5]*m[3]*m[10] - m[9]*m[2]*m[7]   + m[9]*m[3]*m[6];
    inv[7]  =  m[0]*m[6]*m[11]  - m[0]*m[7]*m[10]  - m[4]*m[2]*m[11] + m[4]*m[3]*m[10] + m[8]*m[2]*m[7]   - m[8]*m[3]*m[6];
    inv[11] = -m[0]*m[5]*m[11]  + m[0]*m[7]*m[9]   + m[4]*m[1]*m[11] - m[4]*m[3]*m[9]  - m[8]*m[1]*m[7]   + m[8]*m[3]*m[5];
    inv[15] =  m[0]*m[5]*m[10]  - m[0]*m[6]*m[9]   - m[4]*m[1]*m[10] + m[4]*m[2]*m[9]  + m[8]*m[1]*m[6]   - m[8]*m[2]*m[5];
    float det = m[0]*inv[0] + m[1]*inv[4] + m[2]*inv[8] + m[3]*inv[12];
    float rd = 1.f / det;
    for (int i = 0; i < 16; i++) ws[IRT + t * 16 + i] = inv[i] * rd;
    float r9[9], tv[3];
    for (int i = 0; i < 9; i++) r9[i] = l2cr[t * 9 + i];
    for (int i = 0; i < 3; i++) tv[i] = l2ct[t * 3 + i];
    for (int i = 0; i < 3; i++)
        ws[CAMT + t * 3 + i] = -(r9[0 * 3 + i] * tv[0] + r9[1 * 3 + i] * tv[1] + r9[2 * 3 + i] * tv[2]);
    int b = t / V, v = t % V, cnt = 0;
    for (int p = 0; p < P; p++) cnt += (maskin[(b * P + p) * V + v] > 0) ? 1 : 0;
    ws[MFLAG + t] = (cnt > 1) ? 1.f : 0.f;
}

// ---------------- weight prep: all bf16 [N][K] transposes ----------------
__global__ __launch_bounds__(256) void k_wprep_all(
        const float* kw2, const float* dvw, const float* wo, const float* dw,
        const float* offw, const float* attw, const float* wq, const float* wk, const float* wv,
        const float* w1, const float* w2, bf16* wb) {
    int bid = blockIdx.x, t = threadIdx.x;
    if (bid < 1024) {           // four 256x256 transposes
        int reg = bid >> 8, n = bid & 255;
        const float* src = (reg == 0) ? kw2 : (reg == 1) ? dvw : (reg == 2) ? wo : dw;
        wb[(size_t)reg * 65536 + (size_t)n * 256 + t] = tobf(src[(size_t)t * 256 + n]);
    } else if (bid < 1408) {    // oawT: 384 rows
        int n = bid - 1024;
        float v = (n < 256) ? offw[(size_t)t * 256 + n] : attw[(size_t)t * 128 + (n - 256)];
        wb[OAWT_O + (size_t)n * 256 + t] = tobf(v);
    } else if (bid < 2176) {    // qkvT: 768 rows, K=512
        int n = bid - 1408;
        bf16* dst = wb + QKVT_O + (size_t)n * 512;
        float v0 = (n < 256) ? wq[(size_t)t * 256 + n] : (n < 512) ? wk[(size_t)t * 256 + (n - 256)]
                                                                   : wv[(size_t)t * 256 + (n - 512)];
        dst[t] = tobf(v0);
        float v1 = (n < 256) ? wq[(size_t)t * 256 + n] : (n < 512) ? wk[(size_t)t * 256 + (n - 256)] : 0.f;
        dst[t + 256] = tobf(v1);
    } else if (bid < 3200) {    // w1T: 1024 rows, K=256
        int n = bid - 2176;
        wb[W1T_O + (size_t)n * 256 + t] = tobf(w1[(size_t)t * 1024 + n]);
    } else {                    // w2T: 256 rows, K=1024
        int n = bid - 3200;
        bf16* dst = wb + W2T_O + (size_t)n * 1024;
        for (int kk = 0; kk < 4; kk++)
            dst[t + kk * 256] = tobf(w2[(size_t)(t + kk * 256) * 256 + n]);
    }
}

// ---------------- qpos MLP + x transpose ----------------
__global__ __launch_bounds__(256) void k_qpos(const float* qfeat, const float* qposin,
                                              const float* w1, const float* b1, const float* w2, const float* b2,
                                              float* ws) {
    int row = blockIdx.x, j = threadIdx.x;
    int b = row / P, p = row % P;
    __shared__ __align__(16) float pos[4];
    __shared__ __align__(16) float hid[C];
    if (j < 3) pos[j] = qposin[row * 3 + j];
    __syncthreads();
    float h = b1[j] + pos[0] * w1[0 * C + j] + pos[1] * w1[1 * C + j] + pos[2] * w1[2 * C + j];
    hid[j] = fmaxf(h, 0.f);
    __syncthreads();
    float acc = b2[j] + dotK(hid, w2, j, C, C);
    ws[QPOSo + (size_t)row * C + j] = acc;
    ws[Xo + (size_t)row * C + j] = qfeat[((size_t)b * C + j) * P + p];
}

// ---------------- qkv via one MFMA GEMM: [x|qpos](800x512) @ B'(512x768) ----------------
constexpr int AST2 = 520;   // bf16, 1040 B rows (65*16)
__global__ __launch_bounds__(256) void k_qkv_mfma(const bf16* __restrict__ qkvT, float* ws) {
    __shared__ __align__(16) bf16 As[16 * AST2];
    int row0 = blockIdx.x * 16;
    int t = threadIdx.x;
    for (int rr = 0; rr < 16; rr++) {
        As[rr * AST2 + t]       = tobf(ws[Xo + (size_t)(row0 + rr) * C + t]);
        As[rr * AST2 + 256 + t] = tobf(ws[QPOSo + (size_t)(row0 + rr) * C + t]);
    }
    __syncthreads();
    int wave = t >> 6, lane = t & 63, quad = lane >> 4, l15 = lane & 15;
    int n0 = wave * 192;
    floatx4 acc[12];
    #pragma unroll
    for (int nt = 0; nt < 12; nt++) acc[nt] = (floatx4){0.f, 0.f, 0.f, 0.f};
    for (int kk = 0; kk < 16; kk++) {
        short8 a = *(const short8*)&As[l15 * AST2 + kk * 32 + quad * 8];
        #pragma unroll
        for (int nt = 0; nt < 12; nt++) {
            short8 bf = *(const short8*)&qkvT[(size_t)(n0 + nt * 16 + l15) * 512 + kk * 32 + quad * 8];
            acc[nt] = __builtin_amdgcn_mfma_f32_16x16x32_bf16(a, bf, acc[nt], 0, 0, 0);
        }
    }
    #pragma unroll
    for (int nt = 0; nt < 12; nt++) {
        int n = n0 + nt * 16 + l15;
        int which = n >> 8, c = n & 255;
        size_t dst = (which == 0) ? Qo : (which == 1) ? Ko : VVo;
        int row = row0 + quad * 4;
        #pragma unroll
        for (int u = 0; u < 4; u++)
            ws[dst + (size_t)(row + u) * C + c] = acc[nt][u];
    }
}

// ---------------- attention logits ----------------
__global__ __launch_bounds__(256) void k_logits(float* ws) {
    int bid = blockIdx.x;
    int qi = bid % P, h = (bid / P) % HH, b = bid / (P * HH);
    int j = threadIdx.x;
    __shared__ __align__(16) float qf[Dh];
    if (j < Dh) qf[j] = ws[Qo + ((size_t)(b * P + qi)) * C + h * Dh + j];
    __syncthreads();
    if (j < P) {
        const float* kp = ws + Ko + ((size_t)(b * P + j)) * C + h * Dh;
        float acc = 0.f;
        for (int d = 0; d < Dh; d += 4) {
            float4 kv = *(const float4*)(kp + d);
            float4 qv = *(const float4*)(qf + d);
            acc += kv.x * qv.x + kv.y * qv.y + kv.z * qv.z + kv.w * qv.w;
        }
        ws[LOGo + (size_t)bid * P + j] = acc * 0.17677669529663687f;
    }
}

// ---------------- masked softmax + attn @ V (wave-shuffle reductions) ----------------
__global__ __launch_bounds__(256) void k_sattn(const int* maskin, float* ws) {
    int bid = blockIdx.x;
    int qi = bid % P, h = (bid / P) % HH, v = (bid / (P * HH)) % V, b = bid / (P * HH * V);
    int j = threadIdx.x;
    __shared__ float attn[256];
    __shared__ float red[256];
    __shared__ float rw[8];
    float flag = ws[MFLAG + b * V + v];
    float val = -1e30f;
    if (j < P) {
        float lg = ws[LOGo + ((size_t)(b * HH + h) * P + qi) * P + j];
        bool mk = (flag > 0.5f) && (maskin[(b * P + j) * V + v] > 0);
        val = lg + (mk ? 0.f : -1e9f);
    }
    int wv = j >> 6;
    float m = val;
    #pragma unroll
    for (int off = 32; off > 0; off >>= 1) m = fmaxf(m, __shfl_xor(m, off, 64));
    if ((j & 63) == 0) rw[wv] = m;
    __syncthreads();
    m = fmaxf(fmaxf(rw[0], rw[1]), fmaxf(rw[2], rw[3]));
    float e = (j < P) ? __expf(val - m) : 0.f;
    float s = e;
    #pragma unroll
    for (int off = 32; off > 0; off >>= 1) s += __shfl_xor(s, off, 64);
    if ((j & 63) == 0) rw[4 + wv] = s;
    __syncthreads();
    s = (rw[4] + rw[5]) + (rw[6] + rw[7]);
    attn[j] = e / s;
    __syncthreads();
    int d = j & 31, c = j >> 5;
    const float* vvp = ws + VVo + (size_t)b * P * C + h * Dh + d;
    float acc = 0.f;
    for (int kk = c * 25; kk < c * 25 + 25; ++kk) acc += attn[kk] * vvp[(size_t)kk * C];
    red[j] = acc; __syncthreads();
    if (j < Dh) {
        float s2 = 0.f;
        for (int c2 = 0; c2 < 8; c2++) s2 += red[c2 * 32 + j];
        ws[SAo + ((size_t)((b * V + v) * P + qi)) * C + h * Dh + j] = s2;
    }
}

// ---------------- generic MFMA row-GEMM (K=256,N=256) + residual + LN ----------------
constexpr int GAST = 264;   // bf16 A stride
constexpr int OST = 260;    // f32 out stride
__global__ __launch_bounds__(256) void k_lngemm(const bf16* __restrict__ WT,
        float* ws, size_t aOff, size_t residOff, int residMode, size_t dstOff) {
    __shared__ __align__(16) bf16 As[32 * GAST];
    __shared__ __align__(16) float Os[32 * OST];
    __shared__ float redw[4][8][2];
    __shared__ float mv[8][2];
    int row0 = blockIdx.x * 32;
    int t = threadIdx.x;
    for (int rr = 0; rr < 32; rr++)
        As[rr * GAST + t] = tobf(ws[aOff + (size_t)(row0 + rr) * C + t]);
    __syncthreads();
    int wave = t >> 6, lane = t & 63, quad = lane >> 4, l15 = lane & 15;
    int n0 = wave * 64;
    floatx4 acc[2][4];
    #pragma unroll
    for (int i = 0; i < 2; i++)
        #pragma unroll
        for (int nt = 0; nt < 4; nt++) acc[i][nt] = (floatx4){0.f, 0.f, 0.f, 0.f};
    for (int kk = 0; kk < 8; kk++) {
        short8 a0 = *(const short8*)&As[l15 * GAST + kk * 32 + quad * 8];
        short8 a1 = *(const short8*)&As[(16 + l15) * GAST + kk * 32 + quad * 8];
        #pragma unroll
        for (int nt = 0; nt < 4; nt++) {
            short8 bf = *(const short8*)&WT[(size_t)(n0 + nt * 16 + l15) * 256 + kk * 32 + quad * 8];
            acc[0][nt] = __builtin_amdgcn_mfma_f32_16x16x32_bf16(a0, bf, acc[0][nt], 0, 0, 0);
            acc[1][nt] = __builtin_amdgcn_mfma_f32_16x16x32_bf16(a1, bf, acc[1][nt], 0, 0, 0);
        }
    }
    #pragma unroll
    for (int i = 0; i < 2; i++)
        #pragma unroll
        for (int nt = 0; nt < 4; nt++) {
            int col = n0 + nt * 16 + l15;
            int rl = i * 16 + quad * 4;
            #pragma unroll
            for (int u = 0; u < 4; u++) Os[(rl + u) * OST + col] = acc[i][nt][u];
        }
    __syncthreads();
    int lane2 = t & 63, wv = t >> 6;
    for (int g = 0; g < 4; g++) {
        float rv[8];
        #pragma unroll
        for (int r = 0; r < 8; r++) {
            int grow = row0 + g * 8 + r;
            int ridx = residMode ? ((grow / (P * V)) * P + grow % P) : grow;
            rv[r] = Os[(g * 8 + r) * OST + t] + ws[residOff + (size_t)ridx * C + t];
        }
        #pragma unroll
        for (int r = 0; r < 8; r++) {
            float s = rv[r], q = rv[r] * rv[r];
            for (int off = 32; off > 0; off >>= 1) {
                s += __shfl_down(s, off, 64);
                q += __shfl_down(q, off, 64);
            }
            if (lane2 == 0) { redw[wv][r][0] = s; redw[wv][r][1] = q; }
        }
        __syncthreads();
        if (t < 8) {
            float s = redw[0][t][0] + redw[1][t][0] + redw[2][t][0] + redw[3][t][0];
            float q = redw[0][t][1] + redw[1][t][1] + redw[2][t][1] + redw[3][t][1];
            float mean = s * (1.f / C);
            float var = q * (1.f / C) - mean * mean;
            mv[t][0] = mean; mv[t][1] = rsqrtf(var + 1e-5f);
        }
        __syncthreads();
        #pragma unroll
        for (int r = 0; r < 8; r++) {
            int grow = row0 + g * 8 + r;
            ws[dstOff + (size_t)grow * C + t] = (rv[r] - mv[r][0]) * mv[r][1];
        }
        __syncthreads();
    }
}

// ---------------- reference points ----------------
__global__ __launch_bounds__(256) void k_ref(const float* qposin, const float* rt, float* ws) {
    int tid = blockIdx.x * 256 + threadIdx.x;
    if (tid >= BVP) return;
    int p = tid % P, v = (tid / P) % V, b = tid / (P * V);
    float p0 = qposin[(b * P + p) * 3 + 0];
    float p1 = qposin[(b * P + p) * 3 + 1];
    float p2 = qposin[(b * P + p) * 3 + 2];
    const float* m = rt + (size_t)(b * V + v) * 16;
    float pr[3];
    for (int i = 0; i < 3; i++)
        pr[i] = m[i * 4 + 0] * p0 + m[i * 4 + 1] * p1 + m[i * 4 + 2] * p2 + m[i * 4 + 3];
    ws[REFo + (size_t)tid * 2 + 0] = pr[0] / pr[2] / IMG_W;
    ws[REFo + (size_t)tid * 2 + 1] = pr[1] / pr[2] / IMG_H;
}

// ---------------- off + aw heads via MFMA (N=384) ----------------
constexpr int OAWST = 392;
__global__ __launch_bounds__(256) void k_offaw_mfma(const bf16* __restrict__ oawT,
        const float* __restrict__ ob, const float* __restrict__ ab, float* ws) {
    __shared__ __align__(16) bf16 As[32 * GAST];
    __shared__ __align__(16) float Os[32 * OAWST];
    int row0 = blockIdx.x * 32;
    int t = threadIdx.x;
    for (int rr = 0; rr < 32; rr++) {
        int grow = row0 + rr;
        int ridx = (grow / (P * V)) * P + grow % P;
        As[rr * GAST + t] = tobf(ws[X1o + (size_t)grow * C + t] + ws[QPOSo + (size_t)ridx * C + t]);
    }
    __syncthreads();
    int wave = t >> 6, lane = t & 63, quad = lane >> 4, l15 = lane & 15;
    int n0 = wave * 96;
    floatx4 acc[2][6];
    #pragma unroll
    for (int i = 0; i < 2; i++)
        #pragma unroll
        for (int nt = 0; nt < 6; nt++) acc[i][nt] = (floatx4){0.f, 0.f, 0.f, 0.f};
    for (int kk = 0; kk < 8; kk++) {
        short8 a0 = *(const short8*)&As[l15 * GAST + kk * 32 + quad * 8];
        short8 a1 = *(const short8*)&As[(16 + l15) * GAST + kk * 32 + quad * 8];
        #pragma unroll
        for (int nt = 0; nt < 6; nt++) {
            short8 bf = *(const short8*)&oawT[(size_t)(n0 + nt * 16 + l15) * 256 + kk * 32 + quad * 8];
            acc[0][nt] = __builtin_amdgcn_mfma_f32_16x16x32_bf16(a0, bf, acc[0][nt], 0, 0, 0);
            acc[1][nt] = __builtin_amdgcn_mfma_f32_16x16x32_bf16(a1, bf, acc[1][nt], 0, 0, 0);
        }
    }
    #pragma unroll
    for (int i = 0; i < 2; i++)
        #pragma unroll
        for (int nt = 0; nt < 6; nt++) {
            int col = n0 + nt * 16 + l15;
            int rl = i * 16 + quad * 4;
            #pragma unroll
            for (int u = 0; u < 4; u++) Os[(rl + u) * OAWST + col] = acc[i][nt][u];
        }
    __syncthreads();
    // off: col t, 32 rows
    float obv = ob[t];
    for (int r = 0; r < 32; r++)
        ws[OFFo + (size_t)(row0 + r) * 256 + t] = Os[r * OAWST + t] + obv;
    // aw softmax-16: thread t -> (row r = t>>3, group g = t&7)
    {
        int r = t >> 3, g = t & 7;
        const float* lg = &Os[r * OAWST + 256 + g * 16];
        float mx = -1e30f;
        #pragma unroll
        for (int i = 0; i < 16; i++) mx = fmaxf(mx, lg[i] + ab[g * 16 + i]);
        float s = 0.f;
        float ex[16];
        #pragma unroll
        for (int i = 0; i < 16; i++) { ex[i] = __expf(lg[i] + ab[g * 16 + i] - mx); s += ex[i]; }
        float rs = 1.f / s;
        #pragma unroll
        for (int i = 0; i < 16; i++)
            ws[AWo + (size_t)(row0 + r) * 128 + g * 16 + i] = ex[i] * rs;
    }
}

// ---------------- vals via MFMA: feats add fused into GEMM1 epilogue (registers) ----------------
constexpr int VROWS = 64;
constexpr int ASTR = C + 8;
constexpr int NVT = (L + VROWS - 1) / VROWS;

__global__ __launch_bounds__(256, 4) void k_vals_mfma(
        const float* __restrict__ npos, const float* __restrict__ feats,
        const float* __restrict__ kw1, const float* __restrict__ kb1, const float* __restrict__ kb2,
        const bf16* __restrict__ kw2T, const bf16* __restrict__ dvwT,
        const float* __restrict__ ws, bf16* __restrict__ vals) {
    __shared__ __align__(16) bf16 As[VROWS * ASTR];
    __shared__ float kp6s[VROWS][8];
    __shared__ float kb2s[C];
    int bv = blockIdx.y;
    int l0 = blockIdx.x * VROWS;
    int t = threadIdx.x;
    kb2s[t] = kb2[t];
    if (t < VROWS) {
        int l = min(l0 + t, L - 1);
        float sx = 1.f / (1.f + __expf(-npos[l * 2 + 0])) * IMG_W;
        float sy = 1.f / (1.f + __expf(-npos[l * 2 + 1])) * IMG_H;
        const float* inv = ws + IRT + (size_t)bv * 16;
        #pragma unroll
        for (int i = 0; i < 3; i++)
            kp6s[t][i] = inv[i * 4 + 0] * sx + inv[i * 4 + 1] * sy + inv[i * 4 + 2] + inv[i * 4 + 3];
        #pragma unroll
        for (int i = 0; i < 3; i++) kp6s[t][3 + i] = ws[CAMT + (size_t)bv * 3 + i];
    }
    __syncthreads();
    {
        float w1j[6];
        #pragma unroll
        for (int i = 0; i < 6; i++) w1j[i] = kw1[i * C + t];
        float bb = kb1[t];
        for (int r = 0; r < VROWS; r++) {
            float h = bb;
            #pragma unroll
            for (int i = 0; i < 6; i++) h += kp6s[r][i] * w1j[i];
            As[r * ASTR + t] = tobf(fmaxf(h, 0.f));
        }
    }
    __syncthreads();
    int wave = t >> 6, lane = t & 63;
    int quad = lane >> 4, l15 = lane & 15;
    int mh = (wave >> 1) * 32;
    int nh = (wave & 1) * 128;
    floatx4 acc[2][8];
    #pragma unroll
    for (int i = 0; i < 2; i++)
        #pragma unroll
        for (int nt = 0; nt < 8; nt++) acc[i][nt] = (floatx4){0.f, 0.f, 0.f, 0.f};
    for (int kk = 0; kk < 8; kk++) {
        short8 a0 = *(const short8*)&As[(mh + l15) * ASTR + kk * 32 + quad * 8];
        short8 a1 = *(const short8*)&As[(mh + 16 + l15) * ASTR + kk * 32 + quad * 8];
        #pragma unroll
        for (int nt = 0; nt < 8; nt++) {
            short8 bfr = *(const short8*)&kw2T[(size_t)(nh + nt * 16 + l15) * C + kk * 32 + quad * 8];
            acc[0][nt] = __builtin_amdgcn_mfma_f32_16x16x32_bf16(a0, bfr, acc[0][nt], 0, 0, 0);
            acc[1][nt] = __builtin_amdgcn_mfma_f32_16x16x32_bf16(a1, bfr, acc[1][nt], 0, 0, 0);
        }
    }
    __syncthreads();
    // epilogue: kpe = acc + kb2; fused feats add with per-lane coalesced float4 loads
    // (lane l15 owns channel c; quad u-rows give 4 consecutive l -> 16B along L)
    if (l0 + VROWS <= L) {
        #pragma unroll
        for (int i = 0; i < 2; i++)
            #pragma unroll
            for (int nt = 0; nt < 8; nt++) {
                int c = nh + nt * 16 + l15;
                int rb = mh + i * 16 + quad * 4;
                float4 f = *(const float4*)&feats[((size_t)bv * C + c) * L + l0 + rb];
                float bias = kb2s[c];
                As[(rb + 0) * ASTR + c] = tobf(acc[i][nt][0] + bias + f.x);
                As[(rb + 1) * ASTR + c] = tobf(acc[i][nt][1] + bias + f.y);
                As[(rb + 2) * ASTR + c] = tobf(acc[i][nt][2] + bias + f.z);
                As[(rb + 3) * ASTR + c] = tobf(acc[i][nt][3] + bias + f.w);
            }
    } else {
        #pragma unroll
        for (int i = 0; i < 2; i++)
            #pragma unroll
            for (int nt = 0; nt < 8; nt++) {
                int c = nh + nt * 16 + l15;
                int rb = mh + i * 16 + quad * 4;
                size_t fbase = ((size_t)bv * C + c) * L + l0 + rb;
                float bias = kb2s[c];
                #pragma unroll
                for (int u = 0; u < 4; u++) {
                    float fv = (l0 + rb + u < L) ? feats[fbase + u] : 0.f;
                    As[(rb + u) * ASTR + c] = tobf(acc[i][nt][u] + bias + fv);
                }
            }
    }
    __syncthreads();
    #pragma unroll
    for (int i = 0; i < 2; i++)
        #pragma unroll
        for (int nt = 0; nt < 8; nt++) acc[i][nt] = (floatx4){0.f, 0.f, 0.f, 0.f};
    for (int kk = 0; kk < 8; kk++) {
        short8 a0 = *(const short8*)&As[(mh + l15) * ASTR + kk * 32 + quad * 8];
        short8 a1 = *(const short8*)&As[(mh + 16 + l15) * ASTR + kk * 32 + quad * 8];
        #pragma unroll
        for (int nt = 0; nt < 8; nt++) {
            short8 bfr = *(const short8*)&dvwT[(size_t)(nh + nt * 16 + l15) * C + kk * 32 + quad * 8];
            acc[0][nt] = __builtin_amdgcn_mfma_f32_16x16x32_bf16(a0, bfr, acc[0][nt], 0, 0, 0);
            acc[1][nt] = __builtin_amdgcn_mfma_f32_16x16x32_bf16(a1, bfr, acc[1][nt], 0, 0, 0);
        }
    }
    __syncthreads();
    #pragma unroll
    for (int i = 0; i < 2; i++) {
        #pragma unroll
        for (int nt = 0; nt < 8; nt++) {
            int c = nh + nt * 16 + l15;
            int rb = mh + i * 16 + quad * 4;
            #pragma unroll
            for (int u = 0; u < 4; u++)
                As[(rb + u) * ASTR + c] = tobf(acc[i][nt][u]);
        }
    }
    __syncthreads();
    #pragma unroll
    for (int pass = 0; pass < 8; pass++) {
        int row = pass * 8 + (t >> 5);
        int col = (t & 31) * 8;
        int l = l0 + row;
        if (l < L)
            *(int4*)&vals[((size_t)bv * L + l) * C + col] = *(const int4*)&As[row * ASTR + col];
    }
}

// ---------------- deformable bilinear sampling ----------------
__global__ __launch_bounds__(256) void k_sample(const float* ws, const bf16* vals, float* wsmut) {
    // XCD-chunk swizzle (T1): 4800 % 8 == 0 -> bijective; keeps one (b,v) vals slab per XCD L2
    int bid0 = blockIdx.x;
    int row = (bid0 & 7) * (BVP / 8) + (bid0 >> 3);
    int j = threadIdx.x;
    int h = j >> 5, d = j & 31;
    __shared__ float soff[256];
    __shared__ float sawL[128];
    __shared__ float sref[2];
    soff[j] = ws[OFFo + (size_t)row * 256 + j];
    if (j < 128) sawL[j] = ws[AWo + (size_t)row * 128 + j];
    if (j < 2) sref[j] = ws[REFo + (size_t)row * 2 + j];
    __syncthreads();
    int v = (row / P) % V, b = row / (P * V);
    const bf16* vbase = vals + (size_t)(b * V + v) * L * C + h * Dh + d;
    float acc = 0.f;
    for (int l = 0; l < NLEV; l++) {
        float Wf = (float)cLW[l], Hf = (float)cLH[l];
        int Wi = cLW[l], Hi = cLH[l], S0 = cLS[l];
        for (int n = 0; n < NPTS; n++) {
            int oi = ((h * NLEV + l) * NPTS + n) * 2;
            float lx = sref[0] + soff[oi + 0] / Wf;
            float ly = sref[1] + soff[oi + 1] / Hf;
            float aww = sawL[(h * NLEV + l) * NPTS + n];
            float x = lx * Wf - 0.5f, y = ly * Hf - 0.5f;
            float x0f = floorf(x), y0f = floorf(y);
            float wx = x - x0f, wy = y - y0f;
            int x0 = (int)x0f, y0 = (int)y0f;
            float s = 0.f;
            #pragma unroll
            for (int dy = 0; dy < 2; dy++) {
                #pragma unroll
                for (int dx = 0; dx < 2; dx++) {
                    int xi = x0 + dx, yi = y0 + dy;
                    if (xi >= 0 && xi < Wi && yi >= 0 && yi < Hi) {
                        float wwt = (dx ? wx : 1.f - wx) * (dy ? wy : 1.f - wy);
                        s += wwt * tof(vbase[(size_t)(S0 + yi * Wi + xi) * C]);
                    }
                }
            }
            acc += aww * s;
        }
    }
    wsmut[OUTSo + (size_t)row * C + j] = acc;
}

// ---------------- FFN stage 1: x2 @ w1 + b1, relu -> hidb (bf16) ----------------
__global__ __launch_bounds__(256) void k_ffn1(const bf16* __restrict__ w1T, const float* __restrict__ b1,
                                              float* ws, bf16* hidb) {
    __shared__ __align__(16) bf16 As[32 * GAST];
    __shared__ __align__(16) bf16 Hs[32 * AST2];
    int row0 = blockIdx.x * 32;
    int nb = blockIdx.y * 512;
    int t = threadIdx.x;
    for (int rr = 0; rr < 32; rr++)
        As[rr * GAST + t] = tobf(ws[X2o + (size_t)(row0 + rr) * C + t]);
    __syncthreads();
    int wave = t >> 6, lane = t & 63, quad = lane >> 4, l15 = lane & 15;
    int n0 = wave * 128;
    floatx4 acc[2][8];
    #pragma unroll
    for (int i = 0; i < 2; i++)
        #pragma unroll
        for (int nt = 0; nt < 8; nt++) acc[i][nt] = (floatx4){0.f, 0.f, 0.f, 0.f};
    for (int kk = 0; kk < 8; kk++) {
        short8 a0 = *(const short8*)&As[l15 * GAST + kk * 32 + quad * 8];
        short8 a1 = *(const short8*)&As[(16 + l15) * GAST + kk * 32 + quad * 8];
        #pragma unroll
        for (int nt = 0; nt < 8; nt++) {
            short8 bf = *(const short8*)&w1T[(size_t)(nb + n0 + nt * 16 + l15) * 256 + kk * 32 + quad * 8];
            acc[0][nt] = __builtin_amdgcn_mfma_f32_16x16x32_bf16(a0, bf, acc[0][nt], 0, 0, 0);
            acc[1][nt] = __builtin_amdgcn_mfma_f32_16x16x32_bf16(a1, bf, acc[1][nt], 0, 0, 0);
        }
    }
    #pragma unroll
    for (int i = 0; i < 2; i++)
        #pragma unroll
        for (int nt = 0; nt < 8; nt++) {
            int cl = n0 + nt * 16 + l15;
            float bias = b1[nb + cl];
            int rl = i * 16 + quad * 4;
            #pragma unroll
            for (int u = 0; u < 4; u++)
                Hs[(rl + u) * AST2 + cl] = tobf(fmaxf(acc[i][nt][u] + bias, 0.f));
        }
    __syncthreads();
    #pragma unroll
    for (int pass = 0; pass < 8; pass++) {
        int row = pass * 4 + (t >> 6);
        int col = (t & 63) * 8;
        *(int4*)&hidb[(size_t)(row0 + row) * FFN + nb + col] = *(const int4*)&Hs[row * AST2 + col];
    }
}

// ---------------- FFN stage 2: hidb @ w2 + b2 + x2, LN -> x3 ----------------
__global__ __launch_bounds__(256) void k_ffn2(const bf16* __restrict__ w2T, const float* __restrict__ b2,
                                              const bf16* __restrict__ hidb, float* ws) {
    __shared__ __align__(16) float Os[32 * OST];
    __shared__ float redw[4][8][2];
    __shared__ float mv[8][2];
    int row0 = blockIdx.x * 32;
    int t = threadIdx.x;
    int wave = t >> 6, lane = t & 63, quad = lane >> 4, l15 = lane & 15;
    int n0 = wave * 64;
    floatx4 acc[2][4];
    #pragma unroll
    for (int i = 0; i < 2; i++)
        #pragma unroll
        for (int nt = 0; nt < 4; nt++) acc[i][nt] = (floatx4){0.f, 0.f, 0.f, 0.f};
    for (int kk = 0; kk < 32; kk++) {
        short8 a0 = *(const short8*)&hidb[(size_t)(row0 + l15) * FFN + kk * 32 + quad * 8];
        short8 a1 = *(const short8*)&hidb[(size_t)(row0 + 16 + l15) * FFN + kk * 32 + quad * 8];
        #pragma unroll
        for (int nt = 0; nt < 4; nt++) {
            short8 bf = *(const short8*)&w2T[(size_t)(n0 + nt * 16 + l15) * FFN + kk * 32 + quad * 8];
            acc[0][nt] = __builtin_amdgcn_mfma_f32_16x16x32_bf16(a0, bf, acc[0][nt], 0, 0, 0);
            acc[1][nt] = __builtin_amdgcn_mfma_f32_16x16x32_bf16(a1, bf, acc[1][nt], 0, 0, 0);
        }
    }
    #pragma unroll
    for (int i = 0; i < 2; i++)
        #pragma unroll
        for (int nt = 0; nt < 4; nt++) {
            int col = n0 + nt * 16 + l15;
            float bias = b2[col];
            int rl = i * 16 + quad * 4;
            #pragma unroll
            for (int u = 0; u < 4; u++) Os[(rl + u) * OST + col] = acc[i][nt][u] + bias;
        }
    __syncthreads();
    for (int g = 0; g < 4; g++) {
        float rv[8];
        #pragma unroll
        for (int r = 0; r < 8; r++) {
            int grow = row0 + g * 8 + r;
            rv[r] = Os[(g * 8 + r) * OST + t] + ws[X2o + (size_t)grow * C + t];
        }
        #pragma unroll
        for (int r = 0; r < 8; r++) {
            float s = rv[r], q = rv[r] * rv[r];
            for (int off = 32; off > 0; off >>= 1) {
                s += __shfl_down(s, off, 64);
                q += __shfl_down(q, off, 64);
            }
            if (lane == 0) { redw[wave][r][0] = s; redw[wave][r][1] = q; }
        }
        __syncthreads();
        if (t < 8) {
            float s = redw[0][t][0] + redw[1][t][0] + redw[2][t][0] + redw[3][t][0];
            float q = redw[0][t][1] + redw[1][t][1] + redw[2][t][1] + redw[3][t][1];
            float mean = s * (1.f / C);
            float var = q * (1.f / C) - mean * mean;
            mv[t][0] = mean; mv[t][1] = rsqrtf(var + 1e-5f);
        }
        __syncthreads();
        #pragma unroll
        for (int r = 0; r < 8; r++) {
            int grow = row0 + g * 8 + r;
            ws[X3o + (size_t)grow * C + t] = (rv[r] - mv[r][0]) * mv[r][1];
        }
        __syncthreads();
    }
}

// ---------------- masked view-mean + output0 ----------------
__global__ __launch_bounds__(256) void k_fuse(const int* maskin, float* ws, float* out) {
    int row = blockIdx.x, j = threadIdx.x;
    int b = row / P, p = row % P;
    float s = 0.f, cnt = 0.f;
    for (int v = 0; v < V; v++) {
        bool mk = (maskin[(b * P + p) * V + v] > 0) && (ws[MFLAG + b * V + v] > 0.5f);
        if (mk) {
            s += ws[X3o + ((size_t)((b * V + v) * P + p)) * C + j];
            cnt += 1.f;
        }
    }
    float f = s / (cnt + 1e-4f);
    ws[FUSEDo + (size_t)row * C + j] = f;
    out[O0 + ((size_t)b * C + j) * P + p] = f;
}

// ---------------- pred head + BEV outputs ----------------
__global__ __launch_bounds__(256) void k_pred(const float* w1, const float* b1, const float* w2, const float* b2,
                                              const float* qposin, float* ws, float* out) {
    int row = blockIdx.x, j = threadIdx.x;
    __shared__ __align__(16) float in[C];
    __shared__ float red[256];
    __shared__ float cen[4];
    in[j] = ws[FUSEDo + (size_t)row * C + j];
    __syncthreads();
    float h = fmaxf(b1[j] + dotK(in, w1, j, C, C), 0.f);
    for (int i = 0; i < 3; i++) {
        float s = blockReduceSum(h * w2[j * 3 + i], red);
        if (j == 0) cen[i] = s + b2[i] + qposin[row * 3 + i];
    }
    if (j == 0) {
        float c0 = cen[0], c1 = cen[1], c2 = cen[2];
        float cx = (c0 + 54.f) / 108.f * 135.f;
        float cy = (c1 + 54.f) / 108.f * 135.f;
        int b = row / P, p = row % P;
        out[O1 + (size_t)row * 3 + 0] = c0;
        out[O1 + (size_t)row * 3 + 1] = c1;
        out[O1 + (size_t)row * 3 + 2] = c2;
        out[O2 + (size_t)row * 2 + 0] = cx;
        out[O2 + (size_t)row * 2 + 1] = cy;
        out[O3 + (size_t)b * 2 * P + 0 * P + p] = cx;
        out[O3 + (size_t)b * 2 * P + 1 * P + p] = cy;
        out[O4 + (size_t)b * P + p] = c2;
    }
}

extern "C" void kernel_launch(void* const* d_in, const int* in_sizes, int n_in,
                              void* d_out, int out_size, void* d_ws, size_t ws_size,
                              hipStream_t stream) {
    const float* qfeat  = (const float*)d_in[0];
    const float* qposin = (const float*)d_in[1];
    const int*   maskin = (const int*)d_in[2];
    const float* feats  = (const float*)d_in[3];
    const float* npos   = (const float*)d_in[4];
    const float* rt     = (const float*)d_in[5];
    const float* l2cr   = (const float*)d_in[6];
    const float* l2ct   = (const float*)d_in[7];
    const float* qp_w1 = (const float*)d_in[8],  * qp_b1 = (const float*)d_in[9];
    const float* qp_w2 = (const float*)d_in[10], * qp_b2 = (const float*)d_in[11];
    const float* kp_w1 = (const float*)d_in[12], * kp_b1 = (const float*)d_in[13];
    const float* kp_w2 = (const float*)d_in[14], * kp_b2 = (const float*)d_in[15];
    const float* sa_wq = (const float*)d_in[16], * sa_wk = (const float*)d_in[17];
    const float* sa_wv = (const float*)d_in[18], * sa_wv2 = nullptr;
    const float* sa_wo = (const float*)d_in[19];
    const float* dv_w  = (const float*)d_in[20];
    const float* doffw = (const float*)d_in[21], * doffb = (const float*)d_in[22];
    const float* dattw = (const float*)d_in[23], * dattb = (const float*)d_in[24];
    const float* doutw = (const float*)d_in[25];
    const float* f_w1  = (const float*)d_in[26], * f_b1 = (const float*)d_in[27];
    const float* f_w2  = (const float*)d_in[28], * f_b2 = (const float*)d_in[29];
    const float* p_w1  = (const float*)d_in[30], * p_b1 = (const float*)d_in[31];
    const float* p_w2  = (const float*)d_in[32], * p_b2 = (const float*)d_in[33];
    (void)sa_wv2;

    float* ws = (float*)d_ws;
    bf16* vals = (bf16*)((char*)d_ws + VALS_BYTE_OFF);
    bf16* wb = vals + VALS_ELEMS;
    bf16* hidb = wb + HIDB_O;
    float* out = (float*)d_out;

    k_setup<<<1, 64, 0, stream>>>(rt, l2cr, l2ct, maskin, ws);
    k_wprep_all<<<3456, 256, 0, stream>>>(kp_w2, dv_w, sa_wo, doutw, doffw, dattw,
                                          sa_wq, sa_wk, sa_wv, f_w1, f_w2, wb);
    k_qpos<<<BP, 256, 0, stream>>>(qfeat, qposin, qp_w1, qp_b1, qp_w2, qp_b2, ws);
    k_qkv_mfma<<<BP / 16, 256, 0, stream>>>(wb + QKVT_O, ws);
    k_logits<<<B * HH * P, 256, 0, stream>>>(ws);
    k_sattn<<<B * V * HH * P, 256, 0, stream>>>(maskin, ws);
    k_lngemm<<<BVP / 32, 256, 0, stream>>>(wb + WOT_O, ws, SAo, Xo, 1, X1o);
    k_ref<<<(BVP + 255) / 256, 256, 0, stream>>>(qposin, rt, ws);
    k_offaw_mfma<<<BVP / 32, 256, 0, stream>>>(wb + OAWT_O, doffb, dattb, ws);
    k_vals_mfma<<<dim3(NVT, BV), 256, 0, stream>>>(npos, feats, kp_w1, kp_b1, kp_b2,
                                                   wb + KW2T_O, wb + DVWT_O, ws, vals);
    k_sample<<<BVP, 256, 0, stream>>>(ws, vals, ws);
    k_lngemm<<<BVP / 32, 256, 0, stream>>>(wb + DOUTT_O, ws, OUTSo, X1o, 0, X2o);
    k_ffn1<<<dim3(BVP / 32, 2), 256, 0, stream>>>(wb + W1T_O, f_b1, ws, hidb);
    k_ffn2<<<BVP / 32, 256, 0, stream>>>(wb + W2T_O, f_b2, hidb, ws);
    k_fuse<<<BP, 256, 0, stream>>>(maskin, ws, out);
    k_pred<<<BP, 256, 0, stream>>>(p_w1, p_b1, p_w2, p_b2, qposin, ws, out);
}

// Round 4
// 871.612 us; speedup vs baseline: 1.0135x; 1.0135x over previous
//
#include <hip/hip_runtime.h>
#include <hip/hip_bf16.h>
#include <cstdint>
#include <cstddef>

using bf16 = __hip_bfloat16;
#define DEVFN static __device__ __forceinline__

constexpr int B = 4, V = 6, P = 200, C = 256, HH = 8, Dh = 32, NLEV = 4, NPTS = 4, FFN = 1024;
constexpr int L = 7441;
constexpr int BV = B * V, BP = B * P, BVP = B * V * P, BVL = B * V * L;
constexpr float IMG_W = 800.f, IMG_H = 448.f;

__constant__ int cLH[4] = {56, 28, 14, 7};
__constant__ int cLW[4] = {100, 50, 25, 13};
__constant__ int cLS[4] = {0, 5600, 7000, 7350};

// ---- workspace layout (offsets in floats) ----
constexpr size_t IRT   = 0;
constexpr size_t CAMT  = IRT + (size_t)BV * 16;
constexpr size_t MFLAG = CAMT + (size_t)BV * 3;
constexpr size_t Xo    = MFLAG + BV;
constexpr size_t QPOSo = Xo + (size_t)BP * C;
constexpr size_t Qo    = QPOSo + (size_t)BP * C;
constexpr size_t Ko    = Qo + (size_t)BP * C;
constexpr size_t VVo   = Ko + (size_t)BP * C;
constexpr size_t LOGo  = VVo + (size_t)BP * C;
constexpr size_t SAo   = LOGo + (size_t)B * HH * P * P;
constexpr size_t X1o   = SAo + (size_t)BVP * C;
constexpr size_t REFo  = X1o + (size_t)BVP * C;
constexpr size_t OFFo  = REFo + (size_t)BVP * 2;
constexpr size_t AWo   = OFFo + (size_t)BVP * 256;
constexpr size_t OUTSo = AWo + (size_t)BVP * 128;
constexpr size_t X2o   = OUTSo + (size_t)BVP * C;
constexpr size_t X3o   = X2o + (size_t)BVP * C;
constexpr size_t FUSEDo= X3o + (size_t)BVP * C;
constexpr size_t B2DVo = FUSEDo + (size_t)BP * C;      // b2 @ dvw (256 f32)
constexpr size_t WS_FLOATS = B2DVo + 256;
constexpr size_t VALS_BYTE_OFF = ((WS_FLOATS * 4 + 255) / 256) * 256;
constexpr size_t VALS_ELEMS = (size_t)BVL * C;   // bf16

// bf16 weight region (elements, after vals)
constexpr size_t KW2NB_O = 0;                 // kw2 direct bf16 copy [n][c] (256x256)
constexpr size_t DVWT_O  = 65536;             // dvwT [c_out][k] (256x256)
constexpr size_t WOT_O   = 131072;
constexpr size_t DOUTT_O = 196608;
constexpr size_t OAWT_O  = 262144;            // 384x256
constexpr size_t QKVT_O  = 360448;            // 768x512
constexpr size_t W1T_O   = 753664;            // 1024x256
constexpr size_t W2T_O   = 1015808;           // 256x1024
constexpr size_t HIDB_O  = 1277952;           // 4800x1024 bf16
// kdvT ALIASES the first 65536 elems of hidb: k_wfuse writes it, k_vals reads it,
// and only afterwards does k_ffn1 overwrite hidb (same stream => WAR-safe).
// Keeps total workspace usage identical to the last-passing kernel.
constexpr size_t KDVT_O  = HIDB_O;

// ---- output layout (elements, f32) ----
constexpr size_t O0 = 0;
constexpr size_t O1 = O0 + (size_t)B * C * P;
constexpr size_t O2 = O1 + (size_t)B * P * 3;
constexpr size_t O3 = O2 + (size_t)B * P * 2;
constexpr size_t O4 = O3 + (size_t)B * 2 * P;

DEVFN float tof(bf16 x) { return __bfloat162float(x); }
DEVFN bf16  tobf(float x) { return __float2bfloat16(x); }

typedef __attribute__((ext_vector_type(8))) short short8;
typedef __attribute__((ext_vector_type(4))) float floatx4;

DEVFN float blockReduceSum(float v, float* red) {
    int j = threadIdx.x;
    __syncthreads();
    red[j] = v; __syncthreads();
    for (int s = 128; s > 0; s >>= 1) { if (j < s) red[j] += red[j + s]; __syncthreads(); }
    return red[0];
}

DEVFN float dotK(const float* __restrict__ s, const float* __restrict__ W, int j, int N, int K) {
    float acc = 0.f;
    for (int k = 0; k < K; k += 4) {
        float4 h = *(const float4*)(s + k);
        acc += h.x * W[(size_t)(k + 0) * N + j];
        acc += h.y * W[(size_t)(k + 1) * N + j];
        acc += h.z * W[(size_t)(k + 2) * N + j];
        acc += h.w * W[(size_t)(k + 3) * N + j];
    }
    return acc;
}

// ---------------- setup ----------------
__global__ __launch_bounds__(64) void k_setup(const float* rt, const float* l2cr, const float* l2ct,
                                              const int* maskin, float* ws) {
    int t = threadIdx.x;
    if (t >= BV) return;
    float m[16], inv[16];
    for (int i = 0; i < 16; i++) m[i] = rt[t * 16 + i];
    inv[0]  =  m[5]*m[10]*m[15] - m[5]*m[11]*m[14] - m[9]*m[6]*m[15] + m[9]*m[7]*m[14] + m[13]*m[6]*m[11] - m[13]*m[7]*m[10];
    inv[4]  = -m[4]*m[10]*m[15] + m[4]*m[11]*m[14] + m[8]*m[6]*m[15] - m[8]*m[7]*m[14] - m[12]*m[6]*m[11] + m[12]*m[7]*m[10];
    inv[8]  =  m[4]*m[9]*m[15]  - m[4]*m[11]*m[13] - m[8]*m[5]*m[15] + m[8]*m[7]*m[13] + m[12]*m[5]*m[11] - m[12]*m[7]*m[9];
    inv[12] = -m[4]*m[9]*m[14]  + m[4]*m[10]*m[13] + m[8]*m[5]*m[14] - m[8]*m[6]*m[13] - m[12]*m[5]*m[10] + m[12]*m[6]*m[9];
    inv[1]  = -m[1]*m[10]*m[15] + m[1]*m[11]*m[14] + m[9]*m[2]*m[15] - m[9]*m[3]*m[14] - m[13]*m[2]*m[11] + m[13]*m[3]*m[10];
    inv[5]  =  m[0]*m[10]*m[15] - m[0]*m[11]*m[14] - m[8]*m[2]*m[15] + m[8]*m[3]*m[14] + m[12]*m[2]*m[11] - m[12]*m[3]*m[10];
    inv[9]  = -m[0]*m[9]*m[15]  + m[0]*m[11]*m[13] + m[8]*m[1]*m[15] - m[8]*m[3]*m[13] - m[12]*m[1]*m[11] + m[12]*m[3]*m[9];
    inv[13] =  m[0]*m[9]*m[14]  - m[0]*m[10]*m[13] - m[8]*m[1]*m[14] + m[8]*m[2]*m[13] + m[12]*m[1]*m[10] - m[12]*m[2]*m[9];
    inv[2]  =  m[1]*m[6]*m[15]  - m[1]*m[7]*m[14]  - m[5]*m[2]*m[15] + m[5]*m[3]*m[14] + m[13]*m[2]*m[7]  - m[13]*m[3]*m[6];
    inv[6]  = -m[0]*m[6]*m[15]  + m[0]*m[7]*m[14]  + m[4]*m[2]*m[15] - m[4]*m[3]*m[14] - m[12]*m[2]*m[7]  + m[12]*m[3]*m[6];
    inv[10] =  m[0]*m[5]*m[15]  - m[0]*m[7]*m[13]  - m[4]*m[1]*m[15] + m[4]*m[3]*m[13] + m[12]*m[1]*m[7]  - m[12]*m[3]*m[5];
    inv[14] = -m[0]*m[5]*m[14]  + m[0]*m[6]*m[13]  + m[4]*m[1]*m[14] - m[4]*m[2]*m[13] - m[12]*m[1]*m[6]  + m[12]*m[2]*m[5];
    inv[3]  = -m[1]*m[6]*m[11]  + m[1]*m[7]*m[10]  + m[5]*m[2]*m[11] - m[5]*m[3]*m[10] - m[9]*m[2]*m[7]   + m[9]*m[3]*m[6];
    inv[7]  =  m[0]*m[6]*m[11]  - m[0]*m[7]*m[10]  - m[4]*m[2]*m[11] + m[4]*m[3]*m[10] + m[8]*m[2]*m[7]   - m[8]*m[3]*m[6];
    inv[11] = -m[0]*m[5]*m[11]  + m[0]*m[7]*m[9]   + m[4]*m[1]*m[11] - m[4]*m[3]*m[9]  - m[8]*m[1]*m[7]   + m[8]*m[3]*m[5];
    inv[15] =  m[0]*m[5]*m[10]  - m[0]*m[6]*m[9]   - m[4]*m[1]*m[10] + m[4]*m[2]*m[9]  + m[8]*m[1]*m[6]   - m[8]*m[2]*m[5];
    float det = m[0]*inv[0] + m[1]*inv[4] + m[2]*inv[8] + m[3]*inv[12];
    float rd = 1.f / det;
    for (int i = 0; i < 16; i++) ws[IRT + t * 16 + i] = inv[i] * rd;
    float r9[9], tv[3];
    for (int i = 0; i < 9; i++) r9[i] = l2cr[t * 9 + i];
    for (int i = 0; i < 3; i++) tv[i] = l2ct[t * 3 + i];
    for (int i = 0; i < 3; i++)
        ws[CAMT + t * 3 + i] = -(r9[0 * 3 + i] * tv[0] + r9[1 * 3 + i] * tv[1] + r9[2 * 3 + i] * tv[2]);
    int b = t / V, v = t % V, cnt = 0;
    for (int p = 0; p < P; p++) cnt += (maskin[(b * P + p) * V + v] > 0) ? 1 : 0;
    ws[MFLAG + t] = (cnt > 1) ? 1.f : 0.f;
}

// ---------------- weight prep: bf16 transposes (+ kw2 direct copy) ----------------
__global__ __launch_bounds__(256) void k_wprep_all(
        const float* kw2, const float* dvw, const float* wo, const float* dw,
        const float* offw, const float* attw, const float* wq, const float* wk, const float* wv,
        const float* w1, const float* w2, bf16* wb) {
    int bid = blockIdx.x, t = threadIdx.x;
    if (bid < 1024) {           // slot0: kw2 DIRECT copy; slots 1-3: transposes
        int reg = bid >> 8, n = bid & 255;
        if (reg == 0) {
            wb[(size_t)n * 256 + t] = tobf(kw2[(size_t)n * 256 + t]);   // kw2nb [n][c]
        } else {
            const float* src = (reg == 1) ? dvw : (reg == 2) ? wo : dw;
            wb[(size_t)reg * 65536 + (size_t)n * 256 + t] = tobf(src[(size_t)t * 256 + n]);
        }
    } else if (bid < 1408) {    // oawT: 384 rows
        int n = bid - 1024;
        float v = (n < 256) ? offw[(size_t)t * 256 + n] : attw[(size_t)t * 128 + (n - 256)];
        wb[OAWT_O + (size_t)n * 256 + t] = tobf(v);
    } else if (bid < 2176) {    // qkvT: 768 rows, K=512
        int n = bid - 1408;
        bf16* dst = wb + QKVT_O + (size_t)n * 512;
        float v0 = (n < 256) ? wq[(size_t)t * 256 + n] : (n < 512) ? wk[(size_t)t * 256 + (n - 256)]
                                                                   : wv[(size_t)t * 256 + (n - 512)];
        dst[t] = tobf(v0);
        float v1 = (n < 256) ? wq[(size_t)t * 256 + n] : (n < 512) ? wk[(size_t)t * 256 + (n - 256)] : 0.f;
        dst[t + 256] = tobf(v1);
    } else if (bid < 3200) {    // w1T: 1024 rows, K=256
        int n = bid - 2176;
        wb[W1T_O + (size_t)n * 256 + t] = tobf(w1[(size_t)t * 1024 + n]);
    } else {                    // w2T: 256 rows, K=1024
        int n = bid - 3200;
        bf16* dst = wb + W2T_O + (size_t)n * 1024;
        for (int kk = 0; kk < 4; kk++)
            dst[t + kk * 256] = tobf(w2[(size_t)(t + kk * 256) * 256 + n]);
    }
}

// ---------------- weight fusion: kdvT[c2][n] = sum_c kw2[n][c]*dvw[c][c2]; b2dvw ----------------
constexpr int GAST = 264;   // bf16 A stride
__global__ __launch_bounds__(256) void k_wfuse(const bf16* __restrict__ dvwT, const bf16* __restrict__ kw2nb,
                                               const float* __restrict__ b2, bf16* __restrict__ kdvT,
                                               float* ws) {
    __shared__ __align__(16) bf16 As[32 * GAST];
    int row0 = blockIdx.x * 32;
    int t = threadIdx.x;
    for (int rr = 0; rr < 32; rr++)
        As[rr * GAST + t] = dvwT[(size_t)(row0 + rr) * 256 + t];
    __syncthreads();
    int wave = t >> 6, lane = t & 63, quad = lane >> 4, l15 = lane & 15;
    int n0 = wave * 64;
    floatx4 acc[2][4];
    #pragma unroll
    for (int i = 0; i < 2; i++)
        #pragma unroll
        for (int nt = 0; nt < 4; nt++) acc[i][nt] = (floatx4){0.f, 0.f, 0.f, 0.f};
    for (int kk = 0; kk < 8; kk++) {
        short8 a0 = *(const short8*)&As[l15 * GAST + kk * 32 + quad * 8];
        short8 a1 = *(const short8*)&As[(16 + l15) * GAST + kk * 32 + quad * 8];
        #pragma unroll
        for (int nt = 0; nt < 4; nt++) {
            short8 bf = *(const short8*)&kw2nb[(size_t)(n0 + nt * 16 + l15) * 256 + kk * 32 + quad * 8];
            acc[0][nt] = __builtin_amdgcn_mfma_f32_16x16x32_bf16(a0, bf, acc[0][nt], 0, 0, 0);
            acc[1][nt] = __builtin_amdgcn_mfma_f32_16x16x32_bf16(a1, bf, acc[1][nt], 0, 0, 0);
        }
    }
    #pragma unroll
    for (int i = 0; i < 2; i++)
        #pragma unroll
        for (int nt = 0; nt < 4; nt++) {
            int col = n0 + nt * 16 + l15;
            int rl = i * 16 + quad * 4;
            #pragma unroll
            for (int u = 0; u < 4; u++)
                kdvT[(size_t)(row0 + rl + u) * 256 + col] = tobf(acc[i][nt][u]);
        }
    // b2dvw[c2] = sum_n dvwT[c2][n] * b2[n]
    {
        int r = t >> 3, pp = t & 7;
        float s = 0.f;
        for (int n = pp * 32; n < pp * 32 + 32; n++)
            s += tof(As[r * GAST + n]) * b2[n];
        s += __shfl_down(s, 4, 8);
        s += __shfl_down(s, 2, 8);
        s += __shfl_down(s, 1, 8);
        if (pp == 0) ws[B2DVo + row0 + r] = s;
    }
}

// ---------------- qpos MLP + x transpose ----------------
__global__ __launch_bounds__(256) void k_qpos(const float* qfeat, const float* qposin,
                                              const float* w1, const float* b1, const float* w2, const float* b2,
                                              float* ws) {
    int row = blockIdx.x, j = threadIdx.x;
    int b = row / P, p = row % P;
    __shared__ __align__(16) float pos[4];
    __shared__ __align__(16) float hid[C];
    if (j < 3) pos[j] = qposin[row * 3 + j];
    __syncthreads();
    float h = b1[j] + pos[0] * w1[0 * C + j] + pos[1] * w1[1 * C + j] + pos[2] * w1[2 * C + j];
    hid[j] = fmaxf(h, 0.f);
    __syncthreads();
    float acc = b2[j] + dotK(hid, w2, j, C, C);
    ws[QPOSo + (size_t)row * C + j] = acc;
    ws[Xo + (size_t)row * C + j] = qfeat[((size_t)b * C + j) * P + p];
}

// ---------------- qkv via one MFMA GEMM: [x|qpos](800x512) @ B'(512x768) ----------------
constexpr int AST2 = 520;   // bf16, 1040 B rows (65*16)
__global__ __launch_bounds__(256) void k_qkv_mfma(const bf16* __restrict__ qkvT, float* ws) {
    __shared__ __align__(16) bf16 As[16 * AST2];
    int row0 = blockIdx.x * 16;
    int t = threadIdx.x;
    for (int rr = 0; rr < 16; rr++) {
        As[rr * AST2 + t]       = tobf(ws[Xo + (size_t)(row0 + rr) * C + t]);
        As[rr * AST2 + 256 + t] = tobf(ws[QPOSo + (size_t)(row0 + rr) * C + t]);
    }
    __syncthreads();
    int wave = t >> 6, lane = t & 63, quad = lane >> 4, l15 = lane & 15;
    int n0 = wave * 192;
    floatx4 acc[12];
    #pragma unroll
    for (int nt = 0; nt < 12; nt++) acc[nt] = (floatx4){0.f, 0.f, 0.f, 0.f};
    for (int kk = 0; kk < 16; kk++) {
        short8 a = *(const short8*)&As[l15 * AST2 + kk * 32 + quad * 8];
        #pragma unroll
        for (int nt = 0; nt < 12; nt++) {
            short8 bf = *(const short8*)&qkvT[(size_t)(n0 + nt * 16 + l15) * 512 + kk * 32 + quad * 8];
            acc[nt] = __builtin_amdgcn_mfma_f32_16x16x32_bf16(a, bf, acc[nt], 0, 0, 0);
        }
    }
    #pragma unroll
    for (int nt = 0; nt < 12; nt++) {
        int n = n0 + nt * 16 + l15;
        int which = n >> 8, c = n & 255;
        size_t dst = (which == 0) ? Qo : (which == 1) ? Ko : VVo;
        int row = row0 + quad * 4;
        #pragma unroll
        for (int u = 0; u < 4; u++)
            ws[dst + (size_t)(row + u) * C + c] = acc[nt][u];
    }
}

// ---------------- attention logits ----------------
__global__ __launch_bounds__(256) void k_logits(float* ws) {
    int bid = blockIdx.x;
    int qi = bid % P, h = (bid / P) % HH, b = bid / (P * HH);
    int j = threadIdx.x;
    __shared__ __align__(16) float qf[Dh];
    if (j < Dh) qf[j] = ws[Qo + ((size_t)(b * P + qi)) * C + h * Dh + j];
    __syncthreads();
    if (j < P) {
        const float* kp = ws + Ko + ((size_t)(b * P + j)) * C + h * Dh;
        float acc = 0.f;
        for (int d = 0; d < Dh; d += 4) {
            float4 kv = *(const float4*)(kp + d);
            float4 qv = *(const float4*)(qf + d);
            acc += kv.x * qv.x + kv.y * qv.y + kv.z * qv.z + kv.w * qv.w;
        }
        ws[LOGo + (size_t)bid * P + j] = acc * 0.17677669529663687f;
    }
}

// ---------------- masked softmax + attn @ V (wave-shuffle reductions) ----------------
__global__ __launch_bounds__(256) void k_sattn(const int* maskin, float* ws) {
    int bid = blockIdx.x;
    int qi = bid % P, h = (bid / P) % HH, v = (bid / (P * HH)) % V, b = bid / (P * HH * V);
    int j = threadIdx.x;
    __shared__ float attn[256];
    __shared__ float red[256];
    __shared__ float rw[8];
    float flag = ws[MFLAG + b * V + v];
    float val = -1e30f;
    if (j < P) {
        float lg = ws[LOGo + ((size_t)(b * HH + h) * P + qi) * P + j];
        bool mk = (flag > 0.5f) && (maskin[(b * P + j) * V + v] > 0);
        val = lg + (mk ? 0.f : -1e9f);
    }
    int wv = j >> 6;
    float m = val;
    #pragma unroll
    for (int off = 32; off > 0; off >>= 1) m = fmaxf(m, __shfl_xor(m, off, 64));
    if ((j & 63) == 0) rw[wv] = m;
    __syncthreads();
    m = fmaxf(fmaxf(rw[0], rw[1]), fmaxf(rw[2], rw[3]));
    float e = (j < P) ? __expf(val - m) : 0.f;
    float s = e;
    #pragma unroll
    for (int off = 32; off > 0; off >>= 1) s += __shfl_xor(s, off, 64);
    if ((j & 63) == 0) rw[4 + wv] = s;
    __syncthreads();
    s = (rw[4] + rw[5]) + (rw[6] + rw[7]);
    attn[j] = e / s;
    __syncthreads();
    int d = j & 31, c = j >> 5;
    const float* vvp = ws + VVo + (size_t)b * P * C + h * Dh + d;
    float acc = 0.f;
    for (int kk = c * 25; kk < c * 25 + 25; ++kk) acc += attn[kk] * vvp[(size_t)kk * C];
    red[j] = acc; __syncthreads();
    if (j < Dh) {
        float s2 = 0.f;
        for (int c2 = 0; c2 < 8; c2++) s2 += red[c2 * 32 + j];
        ws[SAo + ((size_t)((b * V + v) * P + qi)) * C + h * Dh + j] = s2;
    }
}

// ---------------- generic MFMA row-GEMM (K=256,N=256) + residual + LN ----------------
constexpr int OST = 260;    // f32 out stride
__global__ __launch_bounds__(256) void k_lngemm(const bf16* __restrict__ WT,
        float* ws, size_t aOff, size_t residOff, int residMode, size_t dstOff) {
    __shared__ __align__(16) bf16 As[32 * GAST];
    __shared__ __align__(16) float Os[32 * OST];
    __shared__ float redw[4][8][2];
    __shared__ float mv[8][2];
    int row0 = blockIdx.x * 32;
    int t = threadIdx.x;
    for (int rr = 0; rr < 32; rr++)
        As[rr * GAST + t] = tobf(ws[aOff + (size_t)(row0 + rr) * C + t]);
    __syncthreads();
    int wave = t >> 6, lane = t & 63, quad = lane >> 4, l15 = lane & 15;
    int n0 = wave * 64;
    floatx4 acc[2][4];
    #pragma unroll
    for (int i = 0; i < 2; i++)
        #pragma unroll
        for (int nt = 0; nt < 4; nt++) acc[i][nt] = (floatx4){0.f, 0.f, 0.f, 0.f};
    for (int kk = 0; kk < 8; kk++) {
        short8 a0 = *(const short8*)&As[l15 * GAST + kk * 32 + quad * 8];
        short8 a1 = *(const short8*)&As[(16 + l15) * GAST + kk * 32 + quad * 8];
        #pragma unroll
        for (int nt = 0; nt < 4; nt++) {
            short8 bf = *(const short8*)&WT[(size_t)(n0 + nt * 16 + l15) * 256 + kk * 32 + quad * 8];
            acc[0][nt] = __builtin_amdgcn_mfma_f32_16x16x32_bf16(a0, bf, acc[0][nt], 0, 0, 0);
            acc[1][nt] = __builtin_amdgcn_mfma_f32_16x16x32_bf16(a1, bf, acc[1][nt], 0, 0, 0);
        }
    }
    #pragma unroll
    for (int i = 0; i < 2; i++)
        #pragma unroll
        for (int nt = 0; nt < 4; nt++) {
            int col = n0 + nt * 16 + l15;
            int rl = i * 16 + quad * 4;
            #pragma unroll
            for (int u = 0; u < 4; u++) Os[(rl + u) * OST + col] = acc[i][nt][u];
        }
    __syncthreads();
    int lane2 = t & 63, wv = t >> 6;
    for (int g = 0; g < 4; g++) {
        float rv[8];
        #pragma unroll
        for (int r = 0; r < 8; r++) {
            int grow = row0 + g * 8 + r;
            int ridx = residMode ? ((grow / (P * V)) * P + grow % P) : grow;
            rv[r] = Os[(g * 8 + r) * OST + t] + ws[residOff + (size_t)ridx * C + t];
        }
        #pragma unroll
        for (int r = 0; r < 8; r++) {
            float s = rv[r], q = rv[r] * rv[r];
            for (int off = 32; off > 0; off >>= 1) {
                s += __shfl_down(s, off, 64);
                q += __shfl_down(q, off, 64);
            }
            if (lane2 == 0) { redw[wv][r][0] = s; redw[wv][r][1] = q; }
        }
        __syncthreads();
        if (t < 8) {
            float s = redw[0][t][0] + redw[1][t][0] + redw[2][t][0] + redw[3][t][0];
            float q = redw[0][t][1] + redw[1][t][1] + redw[2][t][1] + redw[3][t][1];
            float mean = s * (1.f / C);
            float var = q * (1.f / C) - mean * mean;
            mv[t][0] = mean; mv[t][1] = rsqrtf(var + 1e-5f);
        }
        __syncthreads();
        #pragma unroll
        for (int r = 0; r < 8; r++) {
            int grow = row0 + g * 8 + r;
            ws[dstOff + (size_t)grow * C + t] = (rv[r] - mv[r][0]) * mv[r][1];
        }
        __syncthreads();
    }
}

// ---------------- reference points ----------------
__global__ __launch_bounds__(256) void k_ref(const float* qposin, const float* rt, float* ws) {
    int tid = blockIdx.x * 256 + threadIdx.x;
    if (tid >= BVP) return;
    int p = tid % P, v = (tid / P) % V, b = tid / (P * V);
    float p0 = qposin[(b * P + p) * 3 + 0];
    float p1 = qposin[(b * P + p) * 3 + 1];
    float p2 = qposin[(b * P + p) * 3 + 2];
    const float* m = rt + (size_t)(b * V + v) * 16;
    float pr[3];
    for (int i = 0; i < 3; i++)
        pr[i] = m[i * 4 + 0] * p0 + m[i * 4 + 1] * p1 + m[i * 4 + 2] * p2 + m[i * 4 + 3];
    ws[REFo + (size_t)tid * 2 + 0] = pr[0] / pr[2] / IMG_W;
    ws[REFo + (size_t)tid * 2 + 1] = pr[1] / pr[2] / IMG_H;
}

// ---------------- off + aw heads via MFMA (N=384) ----------------
constexpr int OAWST = 392;
__global__ __launch_bounds__(256) void k_offaw_mfma(const bf16* __restrict__ oawT,
        const float* __restrict__ ob, const float* __restrict__ ab, float* ws) {
    __shared__ __align__(16) bf16 As[32 * GAST];
    __shared__ __align__(16) float Os[32 * OAWST];
    int row0 = blockIdx.x * 32;
    int t = threadIdx.x;
    for (int rr = 0; rr < 32; rr++) {
        int grow = row0 + rr;
        int ridx = (grow / (P * V)) * P + grow % P;
        As[rr * GAST + t] = tobf(ws[X1o + (size_t)grow * C + t] + ws[QPOSo + (size_t)ridx * C + t]);
    }
    __syncthreads();
    int wave = t >> 6, lane = t & 63, quad = lane >> 4, l15 = lane & 15;
    int n0 = wave * 96;
    floatx4 acc[2][6];
    #pragma unroll
    for (int i = 0; i < 2; i++)
        #pragma unroll
        for (int nt = 0; nt < 6; nt++) acc[i][nt] = (floatx4){0.f, 0.f, 0.f, 0.f};
    for (int kk = 0; kk < 8; kk++) {
        short8 a0 = *(const short8*)&As[l15 * GAST + kk * 32 + quad * 8];
        short8 a1 = *(const short8*)&As[(16 + l15) * GAST + kk * 32 + quad * 8];
        #pragma unroll
        for (int nt = 0; nt < 6; nt++) {
            short8 bf = *(const short8*)&oawT[(size_t)(n0 + nt * 16 + l15) * 256 + kk * 32 + quad * 8];
            acc[0][nt] = __builtin_amdgcn_mfma_f32_16x16x32_bf16(a0, bf, acc[0][nt], 0, 0, 0);
            acc[1][nt] = __builtin_amdgcn_mfma_f32_16x16x32_bf16(a1, bf, acc[1][nt], 0, 0, 0);
        }
    }
    #pragma unroll
    for (int i = 0; i < 2; i++)
        #pragma unroll
        for (int nt = 0; nt < 6; nt++) {
            int col = n0 + nt * 16 + l15;
            int rl = i * 16 + quad * 4;
            #pragma unroll
            for (int u = 0; u < 4; u++) Os[(rl + u) * OAWST + col] = acc[i][nt][u];
        }
    __syncthreads();
    float obv = ob[t];
    for (int r = 0; r < 32; r++)
        ws[OFFo + (size_t)(row0 + r) * 256 + t] = Os[r * OAWST + t] + obv;
    {
        int r = t >> 3, g = t & 7;
        const float* lg = &Os[r * OAWST + 256 + g * 16];
        float mx = -1e30f;
        #pragma unroll
        for (int i = 0; i < 16; i++) mx = fmaxf(mx, lg[i] + ab[g * 16 + i]);
        float s = 0.f;
        float ex[16];
        #pragma unroll
        for (int i = 0; i < 16; i++) { ex[i] = __expf(lg[i] + ab[g * 16 + i] - mx); s += ex[i]; }
        float rs = 1.f / s;
        #pragma unroll
        for (int i = 0; i < 16; i++)
            ws[AWo + (size_t)(row0 + r) * 128 + g * 16 + i] = ex[i] * rs;
    }
}

// ---------------- vals via MFMA v3: independent GEMMs via kw2@dvw fusion ----------------
// vals = featsT @ dvw + relu(h) @ (kw2@dvw) + b2@dvw   (summed in registers)
constexpr int VROWS = 64;
constexpr int ASTR = C + 8;                 // 264
constexpr int NVT = (L + VROWS - 1) / VROWS;

// XOR swizzle on 16B column-blocks: breaks the 8/16-way conflicts of
// column-major scalar writes while keeping fragment reads ~2-way (free).
DEVFN int swidx(int r, int c) {
    return r * ASTR + ((c & 7) | ((((c >> 3) ^ ((r >> 3) & 7))) << 3));
}
DEVFN int swblk(int r, int cb) {
    return r * ASTR + (((cb ^ ((r >> 3) & 7))) << 3);
}

__global__ __launch_bounds__(256, 4) void k_vals_mfma(
        const float* __restrict__ npos, const float* __restrict__ feats,
        const float* __restrict__ kw1, const float* __restrict__ kb1,
        const bf16* __restrict__ kdvT, const bf16* __restrict__ dvwT,
        const float* __restrict__ ws, bf16* __restrict__ vals) {
    __shared__ __align__(16) bf16 As[VROWS * ASTR];
    __shared__ float kp6s[VROWS][8];
    __shared__ float b2s[C];
    int bv = blockIdx.y;
    int l0 = blockIdx.x * VROWS;
    int t = threadIdx.x;
    bool full = (l0 + VROWS <= L);

    // T14: issue feats batch1 loads (channels 0..127) before anything else
    float4 fb1[8];
    if (full) {
        #pragma unroll
        for (int rnd = 0; rnd < 8; rnd++) {
            int c = rnd * 16 + (t >> 4), ql = (t & 15) * 4;
            fb1[rnd] = *(const float4*)&feats[((size_t)bv * C + c) * L + l0 + ql];
        }
    }
    b2s[t] = ws[B2DVo + t];
    if (t < VROWS) {
        int l = min(l0 + t, L - 1);
        float sx = 1.f / (1.f + __expf(-npos[l * 2 + 0])) * IMG_W;
        float sy = 1.f / (1.f + __expf(-npos[l * 2 + 1])) * IMG_H;
        const float* inv = ws + IRT + (size_t)bv * 16;
        #pragma unroll
        for (int i = 0; i < 3; i++)
            kp6s[t][i] = inv[i * 4 + 0] * sx + inv[i * 4 + 1] * sy + inv[i * 4 + 2] + inv[i * 4 + 3];
        #pragma unroll
        for (int i = 0; i < 3; i++) kp6s[t][3 + i] = ws[CAMT + (size_t)bv * 3 + i];
    }
    __syncthreads();
    // MLP h -> As (swizzled)
    {
        float w1j[6];
        #pragma unroll
        for (int i = 0; i < 6; i++) w1j[i] = kw1[i * C + t];
        float bb = kb1[t];
        for (int r = 0; r < VROWS; r++) {
            float h = bb;
            #pragma unroll
            for (int i = 0; i < 6; i++) h += kp6s[r][i] * w1j[i];
            As[swidx(r, t)] = tobf(fmaxf(h, 0.f));
        }
    }
    __syncthreads();
    int wave = t >> 6, lane = t & 63;
    int quad = lane >> 4, l15 = lane & 15;
    int mh = (wave >> 1) * 32;
    int nh = (wave & 1) * 128;
    floatx4 acc[2][8];
    #pragma unroll
    for (int i = 0; i < 2; i++)
        #pragma unroll
        for (int nt = 0; nt < 8; nt++) acc[i][nt] = (floatx4){0.f, 0.f, 0.f, 0.f};
    // GEMM_h: acc = relu_h @ kw2dvw
    for (int kk = 0; kk < 8; kk++) {
        short8 a0 = *(const short8*)&As[swblk(mh + l15, kk * 4 + quad)];
        short8 a1 = *(const short8*)&As[swblk(mh + 16 + l15, kk * 4 + quad)];
        #pragma unroll
        for (int nt = 0; nt < 8; nt++) {
            short8 bfr = *(const short8*)&kdvT[(size_t)(nh + nt * 16 + l15) * C + kk * 32 + quad * 8];
            acc[0][nt] = __builtin_amdgcn_mfma_f32_16x16x32_bf16(a0, bfr, acc[0][nt], 0, 0, 0);
            acc[1][nt] = __builtin_amdgcn_mfma_f32_16x16x32_bf16(a1, bfr, acc[1][nt], 0, 0, 0);
        }
    }
    __syncthreads();
    // overwrite As with featsT (bf16): batch2 loads first (fly during batch1 writes)
    if (full) {
        float4 fb2[8];
        #pragma unroll
        for (int rnd = 0; rnd < 8; rnd++) {
            int c = 128 + rnd * 16 + (t >> 4), ql = (t & 15) * 4;
            fb2[rnd] = *(const float4*)&feats[((size_t)bv * C + c) * L + l0 + ql];
        }
        #pragma unroll
        for (int rnd = 0; rnd < 8; rnd++) {
            int c = rnd * 16 + (t >> 4), ql = (t & 15) * 4;
            As[swidx(ql + 0, c)] = tobf(fb1[rnd].x);
            As[swidx(ql + 1, c)] = tobf(fb1[rnd].y);
            As[swidx(ql + 2, c)] = tobf(fb1[rnd].z);
            As[swidx(ql + 3, c)] = tobf(fb1[rnd].w);
        }
        #pragma unroll
        for (int rnd = 0; rnd < 8; rnd++) {
            int c = 128 + rnd * 16 + (t >> 4), ql = (t & 15) * 4;
            As[swidx(ql + 0, c)] = tobf(fb2[rnd].x);
            As[swidx(ql + 1, c)] = tobf(fb2[rnd].y);
            As[swidx(ql + 2, c)] = tobf(fb2[rnd].z);
            As[swidx(ql + 3, c)] = tobf(fb2[rnd].w);
        }
    } else {
        for (int rnd = 0; rnd < 16; rnd++) {
            int c = rnd * 16 + (t >> 4), ql = (t & 15) * 4;
            size_t fbase = ((size_t)bv * C + c) * L + l0 + ql;
            #pragma unroll
            for (int u = 0; u < 4; u++) {
                float fv = (l0 + ql + u < L) ? feats[fbase + u] : 0.f;
                As[swidx(ql + u, c)] = tobf(fv);
            }
        }
    }
    __syncthreads();
    // GEMM_f: acc += featsT @ dvw
    for (int kk = 0; kk < 8; kk++) {
        short8 a0 = *(const short8*)&As[swblk(mh + l15, kk * 4 + quad)];
        short8 a1 = *(const short8*)&As[swblk(mh + 16 + l15, kk * 4 + quad)];
        #pragma unroll
        for (int nt = 0; nt < 8; nt++) {
            short8 bfr = *(const short8*)&dvwT[(size_t)(nh + nt * 16 + l15) * C + kk * 32 + quad * 8];
            acc[0][nt] = __builtin_amdgcn_mfma_f32_16x16x32_bf16(a0, bfr, acc[0][nt], 0, 0, 0);
            acc[1][nt] = __builtin_amdgcn_mfma_f32_16x16x32_bf16(a1, bfr, acc[1][nt], 0, 0, 0);
        }
    }
    __syncthreads();
    // epilogue: + b2dvw, bf16, stage to As (swizzled)
    #pragma unroll
    for (int i = 0; i < 2; i++) {
        #pragma unroll
        for (int nt = 0; nt < 8; nt++) {
            int c = nh + nt * 16 + l15;
            int rb = mh + i * 16 + quad * 4;
            float bias = b2s[c];
            #pragma unroll
            for (int u = 0; u < 4; u++)
                As[swidx(rb + u, c)] = tobf(acc[i][nt][u] + bias);
        }
    }
    __syncthreads();
    #pragma unroll
    for (int pass = 0; pass < 8; pass++) {
        int row = pass * 8 + (t >> 5);
        int cb = t & 31;
        int l = l0 + row;
        if (l < L)
            *(int4*)&vals[((size_t)bv * L + l) * C + cb * 8] = *(const int4*)&As[swblk(row, cb)];
    }
}

// ---------------- deformable bilinear sampling ----------------
__global__ __launch_bounds__(256) void k_sample(const float* ws, const bf16* vals, float* wsmut) {
    int bid0 = blockIdx.x;
    int row = (bid0 & 7) * (BVP / 8) + (bid0 >> 3);
    int j = threadIdx.x;
    int h = j >> 5, d = j & 31;
    __shared__ float soff[256];
    __shared__ float sawL[128];
    __shared__ float sref[2];
    soff[j] = ws[OFFo + (size_t)row * 256 + j];
    if (j < 128) sawL[j] = ws[AWo + (size_t)row * 128 + j];
    if (j < 2) sref[j] = ws[REFo + (size_t)row * 2 + j];
    __syncthreads();
    int v = (row / P) % V, b = row / (P * V);
    const bf16* vbase = vals + (size_t)(b * V + v) * L * C + h * Dh + d;
    float acc = 0.f;
    for (int l = 0; l < NLEV; l++) {
        float Wf = (float)cLW[l], Hf = (float)cLH[l];
        int Wi = cLW[l], Hi = cLH[l], S0 = cLS[l];
        for (int n = 0; n < NPTS; n++) {
            int oi = ((h * NLEV + l) * NPTS + n) * 2;
            float lx = sref[0] + soff[oi + 0] / Wf;
            float ly = sref[1] + soff[oi + 1] / Hf;
            float aww = sawL[(h * NLEV + l) * NPTS + n];
            float x = lx * Wf - 0.5f, y = ly * Hf - 0.5f;
            float x0f = floorf(x), y0f = floorf(y);
            float wx = x - x0f, wy = y - y0f;
            int x0 = (int)x0f, y0 = (int)y0f;
            float s = 0.f;
            #pragma unroll
            for (int dy = 0; dy < 2; dy++) {
                #pragma unroll
                for (int dx = 0; dx < 2; dx++) {
                    int xi = x0 + dx, yi = y0 + dy;
                    if (xi >= 0 && xi < Wi && yi >= 0 && yi < Hi) {
                        float wwt = (dx ? wx : 1.f - wx) * (dy ? wy : 1.f - wy);
                        s += wwt * tof(vbase[(size_t)(S0 + yi * Wi + xi) * C]);
                    }
                }
            }
            acc += aww * s;
        }
    }
    wsmut[OUTSo + (size_t)row * C + j] = acc;
}

// ---------------- FFN stage 1: x2 @ w1 + b1, relu -> hidb (bf16) ----------------
__global__ __launch_bounds__(256) void k_ffn1(const bf16* __restrict__ w1T, const float* __restrict__ b1,
                                              float* ws, bf16* hidb) {
    __shared__ __align__(16) bf16 As[32 * GAST];
    __shared__ __align__(16) bf16 Hs[32 * AST2];
    int row0 = blockIdx.x * 32;
    int nb = blockIdx.y * 512;
    int t = threadIdx.x;
    for (int rr = 0; rr < 32; rr++)
        As[rr * GAST + t] = tobf(ws[X2o + (size_t)(row0 + rr) * C + t]);
    __syncthreads();
    int wave = t >> 6, lane = t & 63, quad = lane >> 4, l15 = lane & 15;
    int n0 = wave * 128;
    floatx4 acc[2][8];
    #pragma unroll
    for (int i = 0; i < 2; i++)
        #pragma unroll
        for (int nt = 0; nt < 8; nt++) acc[i][nt] = (floatx4){0.f, 0.f, 0.f, 0.f};
    for (int kk = 0; kk < 8; kk++) {
        short8 a0 = *(const short8*)&As[l15 * GAST + kk * 32 + quad * 8];
        short8 a1 = *(const short8*)&As[(16 + l15) * GAST + kk * 32 + quad * 8];
        #pragma unroll
        for (int nt = 0; nt < 8; nt++) {
            short8 bf = *(const short8*)&w1T[(size_t)(nb + n0 + nt * 16 + l15) * 256 + kk * 32 + quad * 8];
            acc[0][nt] = __builtin_amdgcn_mfma_f32_16x16x32_bf16(a0, bf, acc[0][nt], 0, 0, 0);
            acc[1][nt] = __builtin_amdgcn_mfma_f32_16x16x32_bf16(a1, bf, acc[1][nt], 0, 0, 0);
        }
    }
    #pragma unroll
    for (int i = 0; i < 2; i++)
        #pragma unroll
        for (int nt = 0; nt < 8; nt++) {
            int cl = n0 + nt * 16 + l15;
            float bias = b1[nb + cl];
            int rl = i * 16 + quad * 4;
            #pragma unroll
            for (int u = 0; u < 4; u++)
                Hs[(rl + u) * AST2 + cl] = tobf(fmaxf(acc[i][nt][u] + bias, 0.f));
        }
    __syncthreads();
    #pragma unroll
    for (int pass = 0; pass < 8; pass++) {
        int row = pass * 4 + (t >> 6);
        int col = (t & 63) * 8;
        *(int4*)&hidb[(size_t)(row0 + row) * FFN + nb + col] = *(const int4*)&Hs[row * AST2 + col];
    }
}

// ---------------- FFN stage 2: hidb @ w2 + b2 + x2, LN -> x3 ----------------
__global__ __launch_bounds__(256) void k_ffn2(const bf16* __restrict__ w2T, const float* __restrict__ b2,
                                              const bf16* __restrict__ hidb, float* ws) {
    __shared__ __align__(16) float Os[32 * OST];
    __shared__ float redw[4][8][2];
    __shared__ float mv[8][2];
    int row0 = blockIdx.x * 32;
    int t = threadIdx.x;
    int wave = t >> 6, lane = t & 63, quad = lane >> 4, l15 = lane & 15;
    int n0 = wave * 64;
    floatx4 acc[2][4];
    #pragma unroll
    for (int i = 0; i < 2; i++)
        #pragma unroll
        for (int nt = 0; nt < 4; nt++) acc[i][nt] = (floatx4){0.f, 0.f, 0.f, 0.f};
    for (int kk = 0; kk < 32; kk++) {
        short8 a0 = *(const short8*)&hidb[(size_t)(row0 + l15) * FFN + kk * 32 + quad * 8];
        short8 a1 = *(const short8*)&hidb[(size_t)(row0 + 16 + l15) * FFN + kk * 32 + quad * 8];
        #pragma unroll
        for (int nt = 0; nt < 4; nt++) {
            short8 bf = *(const short8*)&w2T[(size_t)(n0 + nt * 16 + l15) * FFN + kk * 32 + quad * 8];
            acc[0][nt] = __builtin_amdgcn_mfma_f32_16x16x32_bf16(a0, bf, acc[0][nt], 0, 0, 0);
            acc[1][nt] = __builtin_amdgcn_mfma_f32_16x16x32_bf16(a1, bf, acc[1][nt], 0, 0, 0);
        }
    }
    #pragma unroll
    for (int i = 0; i < 2; i++)
        #pragma unroll
        for (int nt = 0; nt < 4; nt++) {
            int col = n0 + nt * 16 + l15;
            float bias = b2[col];
            int rl = i * 16 + quad * 4;
            #pragma unroll
            for (int u = 0; u < 4; u++) Os[(rl + u) * OST + col] = acc[i][nt][u] + bias;
        }
    __syncthreads();
    for (int g = 0; g < 4; g++) {
        float rv[8];
        #pragma unroll
        for (int r = 0; r < 8; r++) {
            int grow = row0 + g * 8 + r;
            rv[r] = Os[(g * 8 + r) * OST + t] + ws[X2o + (size_t)grow * C + t];
        }
        #pragma unroll
        for (int r = 0; r < 8; r++) {
            float s = rv[r], q = rv[r] * rv[r];
            for (int off = 32; off > 0; off >>= 1) {
                s += __shfl_down(s, off, 64);
                q += __shfl_down(q, off, 64);
            }
            if (lane == 0) { redw[wave][r][0] = s; redw[wave][r][1] = q; }
        }
        __syncthreads();
        if (t < 8) {
            float s = redw[0][t][0] + redw[1][t][0] + redw[2][t][0] + redw[3][t][0];
            float q = redw[0][t][1] + redw[1][t][1] + redw[2][t][1] + redw[3][t][1];
            float mean = s * (1.f / C);
            float var = q * (1.f / C) - mean * mean;
            mv[t][0] = mean; mv[t][1] = rsqrtf(var + 1e-5f);
        }
        __syncthreads();
        #pragma unroll
        for (int r = 0; r < 8; r++) {
            int grow = row0 + g * 8 + r;
            ws[X3o + (size_t)grow * C + t] = (rv[r] - mv[r][0]) * mv[r][1];
        }
        __syncthreads();
    }
}

// ---------------- masked view-mean + output0 ----------------
__global__ __launch_bounds__(256) void k_fuse(const int* maskin, float* ws, float* out) {
    int row = blockIdx.x, j = threadIdx.x;
    int b = row / P, p = row % P;
    float s = 0.f, cnt = 0.f;
    for (int v = 0; v < V; v++) {
        bool mk = (maskin[(b * P + p) * V + v] > 0) && (ws[MFLAG + b * V + v] > 0.5f);
        if (mk) {
            s += ws[X3o + ((size_t)((b * V + v) * P + p)) * C + j];
            cnt += 1.f;
        }
    }
    float f = s / (cnt + 1e-4f);
    ws[FUSEDo + (size_t)row * C + j] = f;
    out[O0 + ((size_t)b * C + j) * P + p] = f;
}

// ---------------- pred head + BEV outputs ----------------
__global__ __launch_bounds__(256) void k_pred(const float* w1, const float* b1, const float* w2, const float* b2,
                                              const float* qposin, float* ws, float* out) {
    int row = blockIdx.x, j = threadIdx.x;
    __shared__ __align__(16) float in[C];
    __shared__ float red[256];
    __shared__ float cen[4];
    in[j] = ws[FUSEDo + (size_t)row * C + j];
    __syncthreads();
    float h = fmaxf(b1[j] + dotK(in, w1, j, C, C), 0.f);
    for (int i = 0; i < 3; i++) {
        float s = blockReduceSum(h * w2[j * 3 + i], red);
        if (j == 0) cen[i] = s + b2[i] + qposin[row * 3 + i];
    }
    if (j == 0) {
        float c0 = cen[0], c1 = cen[1], c2 = cen[2];
        float cx = (c0 + 54.f) / 108.f * 135.f;
        float cy = (c1 + 54.f) / 108.f * 135.f;
        int b = row / P, p = row % P;
        out[O1 + (size_t)row * 3 + 0] = c0;
        out[O1 + (size_t)row * 3 + 1] = c1;
        out[O1 + (size_t)row * 3 + 2] = c2;
        out[O2 + (size_t)row * 2 + 0] = cx;
        out[O2 + (size_t)row * 2 + 1] = cy;
        out[O3 + (size_t)b * 2 * P + 0 * P + p] = cx;
        out[O3 + (size_t)b * 2 * P + 1 * P + p] = cy;
        out[O4 + (size_t)b * P + p] = c2;
    }
}

extern "C" void kernel_launch(void* const* d_in, const int* in_sizes, int n_in,
                              void* d_out, int out_size, void* d_ws, size_t ws_size,
                              hipStream_t stream) {
    const float* qfeat  = (const float*)d_in[0];
    const float* qposin = (const float*)d_in[1];
    const int*   maskin = (const int*)d_in[2];
    const float* feats  = (const float*)d_in[3];
    const float* npos   = (const float*)d_in[4];
    const float* rt     = (const float*)d_in[5];
    const float* l2cr   = (const float*)d_in[6];
    const float* l2ct   = (const float*)d_in[7];
    const float* qp_w1 = (const float*)d_in[8],  * qp_b1 = (const float*)d_in[9];
    const float* qp_w2 = (const float*)d_in[10], * qp_b2 = (const float*)d_in[11];
    const float* kp_w1 = (const float*)d_in[12], * kp_b1 = (const float*)d_in[13];
    const float* kp_w2 = (const float*)d_in[14], * kp_b2 = (const float*)d_in[15];
    const float* sa_wq = (const float*)d_in[16], * sa_wk = (const float*)d_in[17];
    const float* sa_wv = (const float*)d_in[18];
    const float* sa_wo = (const float*)d_in[19];
    const float* dv_w  = (const float*)d_in[20];
    const float* doffw = (const float*)d_in[21], * doffb = (const float*)d_in[22];
    const float* dattw = (const float*)d_in[23], * dattb = (const float*)d_in[24];
    const float* doutw = (const float*)d_in[25];
    const float* f_w1  = (const float*)d_in[26], * f_b1 = (const float*)d_in[27];
    const float* f_w2  = (const float*)d_in[28], * f_b2 = (const float*)d_in[29];
    const float* p_w1  = (const float*)d_in[30], * p_b1 = (const float*)d_in[31];
    const float* p_w2  = (const float*)d_in[32], * p_b2 = (const float*)d_in[33];

    float* ws = (float*)d_ws;
    bf16* vals = (bf16*)((char*)d_ws + VALS_BYTE_OFF);
    bf16* wb = vals + VALS_ELEMS;
    bf16* hidb = wb + HIDB_O;
    float* out = (float*)d_out;

    k_setup<<<1, 64, 0, stream>>>(rt, l2cr, l2ct, maskin, ws);
    k_wprep_all<<<3456, 256, 0, stream>>>(kp_w2, dv_w, sa_wo, doutw, doffw, dattw,
                                          sa_wq, sa_wk, sa_wv, f_w1, f_w2, wb);
    k_wfuse<<<8, 256, 0, stream>>>(wb + DVWT_O, wb + KW2NB_O, kp_b2, wb + KDVT_O, ws);
    k_qpos<<<BP, 256, 0, stream>>>(qfeat, qposin, qp_w1, qp_b1, qp_w2, qp_b2, ws);
    k_qkv_mfma<<<BP / 16, 256, 0, stream>>>(wb + QKVT_O, ws);
    k_logits<<<B * HH * P, 256, 0, stream>>>(ws);
    k_sattn<<<B * V * HH * P, 256, 0, stream>>>(maskin, ws);
    k_lngemm<<<BVP / 32, 256, 0, stream>>>(wb + WOT_O, ws, SAo, Xo, 1, X1o);
    k_ref<<<(BVP + 255) / 256, 256, 0, stream>>>(qposin, rt, ws);
    k_offaw_mfma<<<BVP / 32, 256, 0, stream>>>(wb + OAWT_O, doffb, dattb, ws);
    k_vals_mfma<<<dim3(NVT, BV), 256, 0, stream>>>(npos, feats, kp_w1, kp_b1,
                                                   wb + KDVT_O, wb + DVWT_O, ws, vals);
    k_sample<<<BVP, 256, 0, stream>>>(ws, vals, ws);
    k_lngemm<<<BVP / 32, 256, 0, stream>>>(wb + DOUTT_O, ws, OUTSo, X1o, 0, X2o);
    k_ffn1<<<dim3(BVP / 32, 2), 256, 0, stream>>>(wb + W1T_O, f_b1, ws, hidb);
    k_ffn2<<<BVP / 32, 256, 0, stream>>>(wb + W2T_O, f_b2, hidb, ws);
    k_fuse<<<BP, 256, 0, stream>>>(maskin, ws, out);
    k_pred<<<BP, 256, 0, stream>>>(p_w1, p_b1, p_w2, p_b2, qposin, ws, out);
}

// Round 6
// 866.413 us; speedup vs baseline: 1.0195x; 1.0060x over previous
//
#include <hip/hip_runtime.h>
#include <hip/hip_bf16.h>
#include <cstdint>
#include <cstddef>

using bf16 = __hip_bfloat16;
#define DEVFN static __device__ __forceinline__

constexpr int B = 4, V = 6, P = 200, C = 256, HH = 8, Dh = 32, NLEV = 4, NPTS = 4, FFN = 1024;
constexpr int L = 7441;
constexpr int BV = B * V, BP = B * P, BVP = B * V * P, BVL = B * V * L;
constexpr float IMG_W = 800.f, IMG_H = 448.f;

__constant__ int cLH[4] = {56, 28, 14, 7};
__constant__ int cLW[4] = {100, 50, 25, 13};
__constant__ int cLS[4] = {0, 5600, 7000, 7350};

// ---- workspace layout (offsets in floats) ----
constexpr size_t IRT   = 0;
constexpr size_t CAMT  = IRT + (size_t)BV * 16;
constexpr size_t MFLAG = CAMT + (size_t)BV * 3;
constexpr size_t Xo    = MFLAG + BV;
constexpr size_t QPOSo = Xo + (size_t)BP * C;
constexpr size_t Qo    = QPOSo + (size_t)BP * C;
constexpr size_t Ko    = Qo + (size_t)BP * C;
constexpr size_t VVo   = Ko + (size_t)BP * C;
constexpr size_t LOGo  = VVo + (size_t)BP * C;
constexpr size_t SAo   = LOGo + (size_t)B * HH * P * P;
constexpr size_t X1o   = SAo + (size_t)BVP * C;
constexpr size_t REFo  = X1o + (size_t)BVP * C;
constexpr size_t OFFo  = REFo + (size_t)BVP * 2;
constexpr size_t AWo   = OFFo + (size_t)BVP * 256;
constexpr size_t OUTSo = AWo + (size_t)BVP * 128;
constexpr size_t X2o   = OUTSo + (size_t)BVP * C;
constexpr size_t X3o   = X2o + (size_t)BVP * C;
constexpr size_t FUSEDo= X3o + (size_t)BVP * C;
constexpr size_t B2DVo = FUSEDo + (size_t)BP * C;      // b2 @ dvw (256 f32)
constexpr size_t WS_FLOATS = B2DVo + 256;
constexpr size_t VALS_BYTE_OFF = ((WS_FLOATS * 4 + 255) / 256) * 256;
constexpr size_t VALS_ELEMS = (size_t)BVL * C;   // bf16

// bf16 weight region (elements, after vals)
constexpr size_t KW2NB_O = 0;                 // kw2 direct bf16 copy [n][c] (256x256)
constexpr size_t DVWT_O  = 65536;             // dvwT [c_out][k] (256x256)
constexpr size_t WOT_O   = 131072;
constexpr size_t DOUTT_O = 196608;
constexpr size_t OAWT_O  = 262144;            // 384x256
constexpr size_t QKVT_O  = 360448;            // 768x512
constexpr size_t W1T_O   = 753664;            // 1024x256
constexpr size_t W2T_O   = 1015808;           // 256x1024
constexpr size_t HIDB_O  = 1277952;           // 4800x1024 bf16
// kdvT ALIASES the first 65536 elems of hidb (stream-ordered WAR-safe).
constexpr size_t KDVT_O  = HIDB_O;

// ---- output layout (elements, f32) ----
constexpr size_t O0 = 0;
constexpr size_t O1 = O0 + (size_t)B * C * P;
constexpr size_t O2 = O1 + (size_t)B * P * 3;
constexpr size_t O3 = O2 + (size_t)B * P * 2;
constexpr size_t O4 = O3 + (size_t)B * 2 * P;

DEVFN float tof(bf16 x) { return __bfloat162float(x); }
DEVFN bf16  tobf(float x) { return __float2bfloat16(x); }

typedef __attribute__((ext_vector_type(8))) short short8;
typedef __attribute__((ext_vector_type(4))) float floatx4;

DEVFN float blockReduceSum(float v, float* red) {
    int j = threadIdx.x;
    __syncthreads();
    red[j] = v; __syncthreads();
    for (int s = 128; s > 0; s >>= 1) { if (j < s) red[j] += red[j + s]; __syncthreads(); }
    return red[0];
}

DEVFN float dotK(const float* __restrict__ s, const float* __restrict__ W, int j, int N, int K) {
    float acc = 0.f;
    for (int k = 0; k < K; k += 4) {
        float4 h = *(const float4*)(s + k);
        acc += h.x * W[(size_t)(k + 0) * N + j];
        acc += h.y * W[(size_t)(k + 1) * N + j];
        acc += h.z * W[(size_t)(k + 2) * N + j];
        acc += h.w * W[(size_t)(k + 3) * N + j];
    }
    return acc;
}

// ---------------- setup ----------------
__global__ __launch_bounds__(64) void k_setup(const float* rt, const float* l2cr, const float* l2ct,
                                              const int* maskin, float* ws) {
    int t = threadIdx.x;
    if (t >= BV) return;
    float m[16], inv[16];
    for (int i = 0; i < 16; i++) m[i] = rt[t * 16 + i];
    inv[0]  =  m[5]*m[10]*m[15] - m[5]*m[11]*m[14] - m[9]*m[6]*m[15] + m[9]*m[7]*m[14] + m[13]*m[6]*m[11] - m[13]*m[7]*m[10];
    inv[4]  = -m[4]*m[10]*m[15] + m[4]*m[11]*m[14] + m[8]*m[6]*m[15] - m[8]*m[7]*m[14] - m[12]*m[6]*m[11] + m[12]*m[7]*m[10];
    inv[8]  =  m[4]*m[9]*m[15]  - m[4]*m[11]*m[13] - m[8]*m[5]*m[15] + m[8]*m[7]*m[13] + m[12]*m[5]*m[11] - m[12]*m[7]*m[9];
    inv[12] = -m[4]*m[9]*m[14]  + m[4]*m[10]*m[13] + m[8]*m[5]*m[14] - m[8]*m[6]*m[13] - m[12]*m[5]*m[10] + m[12]*m[6]*m[9];
    inv[1]  = -m[1]*m[10]*m[15] + m[1]*m[11]*m[14] + m[9]*m[2]*m[15] - m[9]*m[3]*m[14] - m[13]*m[2]*m[11] + m[13]*m[3]*m[10];
    inv[5]  =  m[0]*m[10]*m[15] - m[0]*m[11]*m[14] - m[8]*m[2]*m[15] + m[8]*m[3]*m[14] + m[12]*m[2]*m[11] - m[12]*m[3]*m[10];
    inv[9]  = -m[0]*m[9]*m[15]  + m[0]*m[11]*m[13] + m[8]*m[1]*m[15] - m[8]*m[3]*m[13] - m[12]*m[1]*m[11] + m[12]*m[3]*m[9];
    inv[13] =  m[0]*m[9]*m[14]  - m[0]*m[10]*m[13] - m[8]*m[1]*m[14] + m[8]*m[2]*m[13] + m[12]*m[1]*m[10] - m[12]*m[2]*m[9];
    inv[2]  =  m[1]*m[6]*m[15]  - m[1]*m[7]*m[14]  - m[5]*m[2]*m[15] + m[5]*m[3]*m[14] + m[13]*m[2]*m[7]  - m[13]*m[3]*m[6];
    inv[6]  = -m[0]*m[6]*m[15]  + m[0]*m[7]*m[14]  + m[4]*m[2]*m[15] - m[4]*m[3]*m[14] - m[12]*m[2]*m[7]  + m[12]*m[3]*m[6];
    inv[10] =  m[0]*m[5]*m[15]  - m[0]*m[7]*m[13]  - m[4]*m[1]*m[15] + m[4]*m[3]*m[13] + m[12]*m[1]*m[7]  - m[12]*m[3]*m[5];
    inv[14] = -m[0]*m[5]*m[14]  + m[0]*m[6]*m[13]  + m[4]*m[1]*m[14] - m[4]*m[2]*m[13] - m[12]*m[1]*m[6]  + m[12]*m[2]*m[5];
    inv[3]  = -m[1]*m[6]*m[11]  + m[1]*m[7]*m[10]  + m[5]*m[2]*m[11] - m[5]*m[3]*m[10] - m[9]*m[2]*m[7]   + m[9]*m[3]*m[6];
    inv[7]  =  m[0]*m[6]*m[11]  - m[0]*m[7]*m[10]  - m[4]*m[2]*m[11] + m[4]*m[3]*m[10] + m[8]*m[2]*m[7]   - m[8]*m[3]*m[6];
    inv[11] = -m[0]*m[5]*m[11]  + m[0]*m[7]*m[9]   + m[4]*m[1]*m[11] - m[4]*m[3]*m[9]  - m[8]*m[1]*m[7]   + m[8]*m[3]*m[5];
    inv[15] =  m[0]*m[5]*m[10]  - m[0]*m[6]*m[9]   - m[4]*m[1]*m[10] + m[4]*m[2]*m[9]  + m[8]*m[1]*m[6]   - m[8]*m[2]*m[5];
    float det = m[0]*inv[0] + m[1]*inv[4] + m[2]*inv[8] + m[3]*inv[12];
    float rd = 1.f / det;
    for (int i = 0; i < 16; i++) ws[IRT + t * 16 + i] = inv[i] * rd;
    float r9[9], tv[3];
    for (int i = 0; i < 9; i++) r9[i] = l2cr[t * 9 + i];
    for (int i = 0; i < 3; i++) tv[i] = l2ct[t * 3 + i];
    for (int i = 0; i < 3; i++)
        ws[CAMT + t * 3 + i] = -(r9[0 * 3 + i] * tv[0] + r9[1 * 3 + i] * tv[1] + r9[2 * 3 + i] * tv[2]);
    int b = t / V, v = t % V, cnt = 0;
    for (int p = 0; p < P; p++) cnt += (maskin[(b * P + p) * V + v] > 0) ? 1 : 0;
    ws[MFLAG + t] = (cnt > 1) ? 1.f : 0.f;
}

// ---------------- weight prep: bf16 transposes (+ kw2 direct copy) ----------------
__global__ __launch_bounds__(256) void k_wprep_all(
        const float* kw2, const float* dvw, const float* wo, const float* dw,
        const float* offw, const float* attw, const float* wq, const float* wk, const float* wv,
        const float* w1, const float* w2, bf16* wb) {
    int bid = blockIdx.x, t = threadIdx.x;
    if (bid < 1024) {           // slot0: kw2 DIRECT copy; slots 1-3: transposes
        int reg = bid >> 8, n = bid & 255;
        if (reg == 0) {
            wb[(size_t)n * 256 + t] = tobf(kw2[(size_t)n * 256 + t]);   // kw2nb [n][c]
        } else {
            const float* src = (reg == 1) ? dvw : (reg == 2) ? wo : dw;
            wb[(size_t)reg * 65536 + (size_t)n * 256 + t] = tobf(src[(size_t)t * 256 + n]);
        }
    } else if (bid < 1408) {    // oawT: 384 rows
        int n = bid - 1024;
        float v = (n < 256) ? offw[(size_t)t * 256 + n] : attw[(size_t)t * 128 + (n - 256)];
        wb[OAWT_O + (size_t)n * 256 + t] = tobf(v);
    } else if (bid < 2176) {    // qkvT: 768 rows, K=512
        int n = bid - 1408;
        bf16* dst = wb + QKVT_O + (size_t)n * 512;
        float v0 = (n < 256) ? wq[(size_t)t * 256 + n] : (n < 512) ? wk[(size_t)t * 256 + (n - 256)]
                                                                   : wv[(size_t)t * 256 + (n - 512)];
        dst[t] = tobf(v0);
        float v1 = (n < 256) ? wq[(size_t)t * 256 + n] : (n < 512) ? wk[(size_t)t * 256 + (n - 256)] : 0.f;
        dst[t + 256] = tobf(v1);
    } else if (bid < 3200) {    // w1T: 1024 rows, K=256
        int n = bid - 2176;
        wb[W1T_O + (size_t)n * 256 + t] = tobf(w1[(size_t)t * 1024 + n]);
    } else {                    // w2T: 256 rows, K=1024
        int n = bid - 3200;
        bf16* dst = wb + W2T_O + (size_t)n * 1024;
        for (int kk = 0; kk < 4; kk++)
            dst[t + kk * 256] = tobf(w2[(size_t)(t + kk * 256) * 256 + n]);
    }
}

// ---------------- weight fusion: kdvT[c2][n] = sum_c kw2[n][c]*dvw[c][c2]; b2dvw ----------------
constexpr int GAST = 264;   // bf16 A stride
__global__ __launch_bounds__(256) void k_wfuse(const bf16* __restrict__ dvwT, const bf16* __restrict__ kw2nb,
                                               const float* __restrict__ b2, bf16* __restrict__ kdvT,
                                               float* ws) {
    __shared__ __align__(16) bf16 As[32 * GAST];
    int row0 = blockIdx.x * 32;
    int t = threadIdx.x;
    for (int rr = 0; rr < 32; rr++)
        As[rr * GAST + t] = dvwT[(size_t)(row0 + rr) * 256 + t];
    __syncthreads();
    int wave = t >> 6, lane = t & 63, quad = lane >> 4, l15 = lane & 15;
    int n0 = wave * 64;
    floatx4 acc[2][4];
    #pragma unroll
    for (int i = 0; i < 2; i++)
        #pragma unroll
        for (int nt = 0; nt < 4; nt++) acc[i][nt] = (floatx4){0.f, 0.f, 0.f, 0.f};
    for (int kk = 0; kk < 8; kk++) {
        short8 a0 = *(const short8*)&As[l15 * GAST + kk * 32 + quad * 8];
        short8 a1 = *(const short8*)&As[(16 + l15) * GAST + kk * 32 + quad * 8];
        #pragma unroll
        for (int nt = 0; nt < 4; nt++) {
            short8 bf = *(const short8*)&kw2nb[(size_t)(n0 + nt * 16 + l15) * 256 + kk * 32 + quad * 8];
            acc[0][nt] = __builtin_amdgcn_mfma_f32_16x16x32_bf16(a0, bf, acc[0][nt], 0, 0, 0);
            acc[1][nt] = __builtin_amdgcn_mfma_f32_16x16x32_bf16(a1, bf, acc[1][nt], 0, 0, 0);
        }
    }
    #pragma unroll
    for (int i = 0; i < 2; i++)
        #pragma unroll
        for (int nt = 0; nt < 4; nt++) {
            int col = n0 + nt * 16 + l15;
            int rl = i * 16 + quad * 4;
            #pragma unroll
            for (int u = 0; u < 4; u++)
                kdvT[(size_t)(row0 + rl + u) * 256 + col] = tobf(acc[i][nt][u]);
        }
    // b2dvw[c2] = sum_n dvwT[c2][n] * b2[n]
    {
        int r = t >> 3, pp = t & 7;
        float s = 0.f;
        for (int n = pp * 32; n < pp * 32 + 32; n++)
            s += tof(As[r * GAST + n]) * b2[n];
        s += __shfl_down(s, 4, 8);
        s += __shfl_down(s, 2, 8);
        s += __shfl_down(s, 1, 8);
        if (pp == 0) ws[B2DVo + row0 + r] = s;
    }
}

// ---------------- qpos MLP + x transpose ----------------
__global__ __launch_bounds__(256) void k_qpos(const float* qfeat, const float* qposin,
                                              const float* w1, const float* b1, const float* w2, const float* b2,
                                              float* ws) {
    int row = blockIdx.x, j = threadIdx.x;
    int b = row / P, p = row % P;
    __shared__ __align__(16) float pos[4];
    __shared__ __align__(16) float hid[C];
    if (j < 3) pos[j] = qposin[row * 3 + j];
    __syncthreads();
    float h = b1[j] + pos[0] * w1[0 * C + j] + pos[1] * w1[1 * C + j] + pos[2] * w1[2 * C + j];
    hid[j] = fmaxf(h, 0.f);
    __syncthreads();
    float acc = b2[j] + dotK(hid, w2, j, C, C);
    ws[QPOSo + (size_t)row * C + j] = acc;
    ws[Xo + (size_t)row * C + j] = qfeat[((size_t)b * C + j) * P + p];
}

// ---------------- qkv via one MFMA GEMM: [x|qpos](800x512) @ B'(512x768) ----------------
constexpr int AST2 = 520;   // bf16, 1040 B rows (65*16)
__global__ __launch_bounds__(256) void k_qkv_mfma(const bf16* __restrict__ qkvT, float* ws) {
    __shared__ __align__(16) bf16 As[16 * AST2];
    int row0 = blockIdx.x * 16;
    int t = threadIdx.x;
    for (int rr = 0; rr < 16; rr++) {
        As[rr * AST2 + t]       = tobf(ws[Xo + (size_t)(row0 + rr) * C + t]);
        As[rr * AST2 + 256 + t] = tobf(ws[QPOSo + (size_t)(row0 + rr) * C + t]);
    }
    __syncthreads();
    int wave = t >> 6, lane = t & 63, quad = lane >> 4, l15 = lane & 15;
    int n0 = wave * 192;
    floatx4 acc[12];
    #pragma unroll
    for (int nt = 0; nt < 12; nt++) acc[nt] = (floatx4){0.f, 0.f, 0.f, 0.f};
    for (int kk = 0; kk < 16; kk++) {
        short8 a = *(const short8*)&As[l15 * AST2 + kk * 32 + quad * 8];
        #pragma unroll
        for (int nt = 0; nt < 12; nt++) {
            short8 bf = *(const short8*)&qkvT[(size_t)(n0 + nt * 16 + l15) * 512 + kk * 32 + quad * 8];
            acc[nt] = __builtin_amdgcn_mfma_f32_16x16x32_bf16(a, bf, acc[nt], 0, 0, 0);
        }
    }
    #pragma unroll
    for (int nt = 0; nt < 12; nt++) {
        int n = n0 + nt * 16 + l15;
        int which = n >> 8, c = n & 255;
        size_t dst = (which == 0) ? Qo : (which == 1) ? Ko : VVo;
        int row = row0 + quad * 4;
        #pragma unroll
        for (int u = 0; u < 4; u++)
            ws[dst + (size_t)(row + u) * C + c] = acc[nt][u];
    }
}

// ---------------- attention logits ----------------
__global__ __launch_bounds__(256) void k_logits(float* ws) {
    int bid = blockIdx.x;
    int qi = bid % P, h = (bid / P) % HH, b = bid / (P * HH);
    int j = threadIdx.x;
    __shared__ __align__(16) float qf[Dh];
    if (j < Dh) qf[j] = ws[Qo + ((size_t)(b * P + qi)) * C + h * Dh + j];
    __syncthreads();
    if (j < P) {
        const float* kp = ws + Ko + ((size_t)(b * P + j)) * C + h * Dh;
        float acc = 0.f;
        for (int d = 0; d < Dh; d += 4) {
            float4 kv = *(const float4*)(kp + d);
            float4 qv = *(const float4*)(qf + d);
            acc += kv.x * qv.x + kv.y * qv.y + kv.z * qv.z + kv.w * qv.w;
        }
        ws[LOGo + (size_t)bid * P + j] = acc * 0.17677669529663687f;
    }
}

// ---------------- masked softmax + attn @ V, all 6 views per block ----------------
// VV element loaded ONCE and reused for 6 views (was 6x traffic + 6x blocks).
__global__ __launch_bounds__(256) void k_sattn(const int* maskin, float* ws) {
    int bid = blockIdx.x;              // B*HH*P
    int qi = bid % P, h = (bid / P) % HH, b = bid / (P * HH);
    int j = threadIdx.x;
    __shared__ float attn[V][256];
    __shared__ float red6[V * 8 * 32];
    __shared__ float rwm[V][4], rws[V][4];
    int wv = j >> 6;
    float lg = (j < P) ? ws[LOGo + ((size_t)(b * HH + h) * P + qi) * P + j] : 0.f;
    float val[V];
    #pragma unroll
    for (int v = 0; v < V; v++) {
        bool mk = false;
        if (j < P) {
            float flag = ws[MFLAG + b * V + v];
            mk = (flag > 0.5f) && (maskin[(b * P + j) * V + v] > 0);
        }
        val[v] = (j < P) ? (lg + (mk ? 0.f : -1e9f)) : -1e30f;
    }
    #pragma unroll
    for (int v = 0; v < V; v++) {
        float m = val[v];
        #pragma unroll
        for (int off = 32; off > 0; off >>= 1) m = fmaxf(m, __shfl_xor(m, off, 64));
        if ((j & 63) == 0) rwm[v][wv] = m;
    }
    __syncthreads();
    float ee[V];
    #pragma unroll
    for (int v = 0; v < V; v++) {
        float m = fmaxf(fmaxf(rwm[v][0], rwm[v][1]), fmaxf(rwm[v][2], rwm[v][3]));
        ee[v] = (j < P) ? __expf(val[v] - m) : 0.f;
        float s = ee[v];
        #pragma unroll
        for (int off = 32; off > 0; off >>= 1) s += __shfl_xor(s, off, 64);
        if ((j & 63) == 0) rws[v][wv] = s;
    }
    __syncthreads();
    #pragma unroll
    for (int v = 0; v < V; v++) {
        float s = (rws[v][0] + rws[v][1]) + (rws[v][2] + rws[v][3]);
        attn[v][j] = ee[v] / s;
    }
    __syncthreads();
    int d = j & 31, c = j >> 5;
    const float* vvp = ws + VVo + (size_t)b * P * C + h * Dh + d;
    float acc[V];
    #pragma unroll
    for (int v = 0; v < V; v++) acc[v] = 0.f;
    for (int kk = c * 25; kk < c * 25 + 25; ++kk) {
        float vv = vvp[(size_t)kk * C];
        #pragma unroll
        for (int v = 0; v < V; v++) acc[v] += attn[v][kk] * vv;
    }
    #pragma unroll
    for (int v = 0; v < V; v++) red6[(v * 8 + c) * 32 + d] = acc[v];
    __syncthreads();
    if (j < V * 32) {
        int v = j >> 5, dd = j & 31;
        float s2 = 0.f;
        #pragma unroll
        for (int c2 = 0; c2 < 8; c2++) s2 += red6[(v * 8 + c2) * 32 + dd];
        ws[SAo + ((size_t)((b * V + v) * P + qi)) * C + h * Dh + dd] = s2;
    }
}

// ---------------- generic MFMA row-GEMM (K=256,N=256) + residual + LN ----------------
constexpr int OST = 260;    // f32 out stride
__global__ __launch_bounds__(256) void k_lngemm(const bf16* __restrict__ WT,
        float* ws, size_t aOff, size_t residOff, int residMode, size_t dstOff) {
    __shared__ __align__(16) bf16 As[32 * GAST];
    __shared__ __align__(16) float Os[32 * OST];
    __shared__ float redw[4][8][2];
    __shared__ float mv[8][2];
    int row0 = blockIdx.x * 32;
    int t = threadIdx.x;
    for (int rr = 0; rr < 32; rr++)
        As[rr * GAST + t] = tobf(ws[aOff + (size_t)(row0 + rr) * C + t]);
    __syncthreads();
    int wave = t >> 6, lane = t & 63, quad = lane >> 4, l15 = lane & 15;
    int n0 = wave * 64;
    floatx4 acc[2][4];
    #pragma unroll
    for (int i = 0; i < 2; i++)
        #pragma unroll
        for (int nt = 0; nt < 4; nt++) acc[i][nt] = (floatx4){0.f, 0.f, 0.f, 0.f};
    for (int kk = 0; kk < 8; kk++) {
        short8 a0 = *(const short8*)&As[l15 * GAST + kk * 32 + quad * 8];
        short8 a1 = *(const short8*)&As[(16 + l15) * GAST + kk * 32 + quad * 8];
        #pragma unroll
        for (int nt = 0; nt < 4; nt++) {
            short8 bf = *(const short8*)&WT[(size_t)(n0 + nt * 16 + l15) * 256 + kk * 32 + quad * 8];
            acc[0][nt] = __builtin_amdgcn_mfma_f32_16x16x32_bf16(a0, bf, acc[0][nt], 0, 0, 0);
            acc[1][nt] = __builtin_amdgcn_mfma_f32_16x16x32_bf16(a1, bf, acc[1][nt], 0, 0, 0);
        }
    }
    #pragma unroll
    for (int i = 0; i < 2; i++)
        #pragma unroll
        for (int nt = 0; nt < 4; nt++) {
            int col = n0 + nt * 16 + l15;
            int rl = i * 16 + quad * 4;
            #pragma unroll
            for (int u = 0; u < 4; u++) Os[(rl + u) * OST + col] = acc[i][nt][u];
        }
    __syncthreads();
    int lane2 = t & 63, wv = t >> 6;
    for (int g = 0; g < 4; g++) {
        float rv[8];
        #pragma unroll
        for (int r = 0; r < 8; r++) {
            int grow = row0 + g * 8 + r;
            int ridx = residMode ? ((grow / (P * V)) * P + grow % P) : grow;
            rv[r] = Os[(g * 8 + r) * OST + t] + ws[residOff + (size_t)ridx * C + t];
        }
        #pragma unroll
        for (int r = 0; r < 8; r++) {
            float s = rv[r], q = rv[r] * rv[r];
            for (int off = 32; off > 0; off >>= 1) {
                s += __shfl_down(s, off, 64);
                q += __shfl_down(q, off, 64);
            }
            if (lane2 == 0) { redw[wv][r][0] = s; redw[wv][r][1] = q; }
        }
        __syncthreads();
        if (t < 8) {
            float s = redw[0][t][0] + redw[1][t][0] + redw[2][t][0] + redw[3][t][0];
            float q = redw[0][t][1] + redw[1][t][1] + redw[2][t][1] + redw[3][t][1];
            float mean = s * (1.f / C);
            float var = q * (1.f / C) - mean * mean;
            mv[t][0] = mean; mv[t][1] = rsqrtf(var + 1e-5f);
        }
        __syncthreads();
        #pragma unroll
        for (int r = 0; r < 8; r++) {
            int grow = row0 + g * 8 + r;
            ws[dstOff + (size_t)grow * C + t] = (rv[r] - mv[r][0]) * mv[r][1];
        }
        __syncthreads();
    }
}

// ---------------- reference points ----------------
__global__ __launch_bounds__(256) void k_ref(const float* qposin, const float* rt, float* ws) {
    int tid = blockIdx.x * 256 + threadIdx.x;
    if (tid >= BVP) return;
    int p = tid % P, v = (tid / P) % V, b = tid / (P * V);
    float p0 = qposin[(b * P + p) * 3 + 0];
    float p1 = qposin[(b * P + p) * 3 + 1];
    float p2 = qposin[(b * P + p) * 3 + 2];
    const float* m = rt + (size_t)(b * V + v) * 16;
    float pr[3];
    for (int i = 0; i < 3; i++)
        pr[i] = m[i * 4 + 0] * p0 + m[i * 4 + 1] * p1 + m[i * 4 + 2] * p2 + m[i * 4 + 3];
    ws[REFo + (size_t)tid * 2 + 0] = pr[0] / pr[2] / IMG_W;
    ws[REFo + (size_t)tid * 2 + 1] = pr[1] / pr[2] / IMG_H;
}

// ---------------- off + aw heads via MFMA (N=384) ----------------
constexpr int OAWST = 392;
__global__ __launch_bounds__(256) void k_offaw_mfma(const bf16* __restrict__ oawT,
        const float* __restrict__ ob, const float* __restrict__ ab, float* ws) {
    __shared__ __align__(16) bf16 As[32 * GAST];
    __shared__ __align__(16) float Os[32 * OAWST];
    int row0 = blockIdx.x * 32;
    int t = threadIdx.x;
    for (int rr = 0; rr < 32; rr++) {
        int grow = row0 + rr;
        int ridx = (grow / (P * V)) * P + grow % P;
        As[rr * GAST + t] = tobf(ws[X1o + (size_t)grow * C + t] + ws[QPOSo + (size_t)ridx * C + t]);
    }
    __syncthreads();
    int wave = t >> 6, lane = t & 63, quad = lane >> 4, l15 = lane & 15;
    int n0 = wave * 96;
    floatx4 acc[2][6];
    #pragma unroll
    for (int i = 0; i < 2; i++)
        #pragma unroll
        for (int nt = 0; nt < 6; nt++) acc[i][nt] = (floatx4){0.f, 0.f, 0.f, 0.f};
    for (int kk = 0; kk < 8; kk++) {
        short8 a0 = *(const short8*)&As[l15 * GAST + kk * 32 + quad * 8];
        short8 a1 = *(const short8*)&As[(16 + l15) * GAST + kk * 32 + quad * 8];
        #pragma unroll
        for (int nt = 0; nt < 6; nt++) {
            short8 bf = *(const short8*)&oawT[(size_t)(n0 + nt * 16 + l15) * 256 + kk * 32 + quad * 8];
            acc[0][nt] = __builtin_amdgcn_mfma_f32_16x16x32_bf16(a0, bf, acc[0][nt], 0, 0, 0);
            acc[1][nt] = __builtin_amdgcn_mfma_f32_16x16x32_bf16(a1, bf, acc[1][nt], 0, 0, 0);
        }
    }
    #pragma unroll
    for (int i = 0; i < 2; i++)
        #pragma unroll
        for (int nt = 0; nt < 6; nt++) {
            int col = n0 + nt * 16 + l15;
            int rl = i * 16 + quad * 4;
            #pragma unroll
            for (int u = 0; u < 4; u++) Os[(rl + u) * OAWST + col] = acc[i][nt][u];
        }
    __syncthreads();
    float obv = ob[t];
    for (int r = 0; r < 32; r++)
        ws[OFFo + (size_t)(row0 + r) * 256 + t] = Os[r * OAWST + t] + obv;
    {
        int r = t >> 3, g = t & 7;
        const float* lg = &Os[r * OAWST + 256 + g * 16];
        float mx = -1e30f;
        #pragma unroll
        for (int i = 0; i < 16; i++) mx = fmaxf(mx, lg[i] + ab[g * 16 + i]);
        float s = 0.f;
        float ex[16];
        #pragma unroll
        for (int i = 0; i < 16; i++) { ex[i] = __expf(lg[i] + ab[g * 16 + i] - mx); s += ex[i]; }
        float rs = 1.f / s;
        #pragma unroll
        for (int i = 0; i < 16; i++)
            ws[AWo + (size_t)(row0 + r) * 128 + g * 16 + i] = ex[i] * rs;
    }
}

// ---------------- vals via MFMA v4: kdv fusion, LDS staging, NO register prefetch ----------------
// vals = featsT @ dvw + relu(h) @ (kw2@dvw) + b2@dvw   (summed in registers)
constexpr int VROWS = 64;
constexpr int ASTR = C + 8;                 // 264
constexpr int NVT = (L + VROWS - 1) / VROWS;

// XOR swizzle on 16B column-blocks.
DEVFN int swidx(int r, int c) {
    return r * ASTR + ((c & 7) | ((((c >> 3) ^ ((r >> 3) & 7))) << 3));
}
DEVFN int swblk(int r, int cb) {
    return r * ASTR + (((cb ^ ((r >> 3) & 7))) << 3);
}

__global__ __launch_bounds__(256, 4) void k_vals_mfma(
        const float* __restrict__ npos, const float* __restrict__ feats,
        const float* __restrict__ kw1, const float* __restrict__ kb1,
        const bf16* __restrict__ kdvT, const bf16* __restrict__ dvwT,
        const float* __restrict__ ws, bf16* __restrict__ vals) {
    __shared__ __align__(16) bf16 As[VROWS * ASTR];
    __shared__ float kp6s[VROWS][8];
    __shared__ float b2s[C];
    int bv = blockIdx.y;
    int l0 = blockIdx.x * VROWS;
    int t = threadIdx.x;
    bool full = (l0 + VROWS <= L);

    b2s[t] = ws[B2DVo + t];
    if (t < VROWS) {
        int l = min(l0 + t, L - 1);
        float sx = 1.f / (1.f + __expf(-npos[l * 2 + 0])) * IMG_W;
        float sy = 1.f / (1.f + __expf(-npos[l * 2 + 1])) * IMG_H;
        const float* inv = ws + IRT + (size_t)bv * 16;
        #pragma unroll
        for (int i = 0; i < 3; i++)
            kp6s[t][i] = inv[i * 4 + 0] * sx + inv[i * 4 + 1] * sy + inv[i * 4 + 2] + inv[i * 4 + 3];
        #pragma unroll
        for (int i = 0; i < 3; i++) kp6s[t][3 + i] = ws[CAMT + (size_t)bv * 3 + i];
    }
    __syncthreads();
    // MLP h -> As (swizzled)
    {
        float w1j[6];
        #pragma unroll
        for (int i = 0; i < 6; i++) w1j[i] = kw1[i * C + t];
        float bb = kb1[t];
        for (int r = 0; r < VROWS; r++) {
            float h = bb;
            #pragma unroll
            for (int i = 0; i < 6; i++) h += kp6s[r][i] * w1j[i];
            As[swidx(r, t)] = tobf(fmaxf(h, 0.f));
        }
    }
    __syncthreads();
    int wave = t >> 6, lane = t & 63;
    int quad = lane >> 4, l15 = lane & 15;
    int mh = (wave >> 1) * 32;
    int nh = (wave & 1) * 128;
    floatx4 acc[2][8];
    #pragma unroll
    for (int i = 0; i < 2; i++)
        #pragma unroll
        for (int nt = 0; nt < 8; nt++) acc[i][nt] = (floatx4){0.f, 0.f, 0.f, 0.f};
    // GEMM_h: acc = relu_h @ kw2dvw
    for (int kk = 0; kk < 8; kk++) {
        short8 a0 = *(const short8*)&As[swblk(mh + l15, kk * 4 + quad)];
        short8 a1 = *(const short8*)&As[swblk(mh + 16 + l15, kk * 4 + quad)];
        #pragma unroll
        for (int nt = 0; nt < 8; nt++) {
            short8 bfr = *(const short8*)&kdvT[(size_t)(nh + nt * 16 + l15) * C + kk * 32 + quad * 8];
            acc[0][nt] = __builtin_amdgcn_mfma_f32_16x16x32_bf16(a0, bfr, acc[0][nt], 0, 0, 0);
            acc[1][nt] = __builtin_amdgcn_mfma_f32_16x16x32_bf16(a1, bfr, acc[1][nt], 0, 0, 0);
        }
    }
    __syncthreads();
    // feats -> As (swizzled); 256B-contiguous read per 16-lane group, no reg prefetch
    if (full) {
        #pragma unroll
        for (int rnd = 0; rnd < 16; rnd++) {
            int q = rnd * 256 + t;
            int c = q >> 4, ql = (q & 15) * 4;
            float4 f = *(const float4*)&feats[((size_t)bv * C + c) * L + l0 + ql];
            As[swidx(ql + 0, c)] = tobf(f.x);
            As[swidx(ql + 1, c)] = tobf(f.y);
            As[swidx(ql + 2, c)] = tobf(f.z);
            As[swidx(ql + 3, c)] = tobf(f.w);
        }
    } else {
        for (int rnd = 0; rnd < 16; rnd++) {
            int q = rnd * 256 + t;
            int c = q >> 4, ql = (q & 15) * 4;
            size_t fbase = ((size_t)bv * C + c) * L + l0 + ql;
            #pragma unroll
            for (int u = 0; u < 4; u++) {
                float fv = (l0 + ql + u < L) ? feats[fbase + u] : 0.f;
                As[swidx(ql + u, c)] = tobf(fv);
            }
        }
    }
    __syncthreads();
    // GEMM_f: acc += featsT @ dvw
    for (int kk = 0; kk < 8; kk++) {
        short8 a0 = *(const short8*)&As[swblk(mh + l15, kk * 4 + quad)];
        short8 a1 = *(const short8*)&As[swblk(mh + 16 + l15, kk * 4 + quad)];
        #pragma unroll
        for (int nt = 0; nt < 8; nt++) {
            short8 bfr = *(const short8*)&dvwT[(size_t)(nh + nt * 16 + l15) * C + kk * 32 + quad * 8];
            acc[0][nt] = __builtin_amdgcn_mfma_f32_16x16x32_bf16(a0, bfr, acc[0][nt], 0, 0, 0);
            acc[1][nt] = __builtin_amdgcn_mfma_f32_16x16x32_bf16(a1, bfr, acc[1][nt], 0, 0, 0);
        }
    }
    __syncthreads();
    // epilogue: + b2dvw, bf16, stage to As (swizzled)
    #pragma unroll
    for (int i = 0; i < 2; i++) {
        #pragma unroll
        for (int nt = 0; nt < 8; nt++) {
            int c = nh + nt * 16 + l15;
            int rb = mh + i * 16 + quad * 4;
            float bias = b2s[c];
            #pragma unroll
            for (int u = 0; u < 4; u++)
                As[swidx(rb + u, c)] = tobf(acc[i][nt][u] + bias);
        }
    }
    __syncthreads();
    #pragma unroll
    for (int pass = 0; pass < 8; pass++) {
        int row = pass * 8 + (t >> 5);
        int cb = t & 31;
        int l = l0 + row;
        if (l < L)
            *(int4*)&vals[((size_t)bv * L + l) * C + cb * 8] = *(const int4*)&As[swblk(row, cb)];
    }
}

// ---------------- deformable bilinear sampling ----------------
__global__ __launch_bounds__(256) void k_sample(const float* ws, const bf16* vals, float* wsmut) {
    int bid0 = blockIdx.x;
    int row = (bid0 & 7) * (BVP / 8) + (bid0 >> 3);
    int j = threadIdx.x;
    int h = j >> 5, d = j & 31;
    __shared__ float soff[256];
    __shared__ float sawL[128];
    __shared__ float sref[2];
    soff[j] = ws[OFFo + (size_t)row * 256 + j];
    if (j < 128) sawL[j] = ws[AWo + (size_t)row * 128 + j];
    if (j < 2) sref[j] = ws[REFo + (size_t)row * 2 + j];
    __syncthreads();
    int v = (row / P) % V, b = row / (P * V);
    const bf16* vbase = vals + (size_t)(b * V + v) * L * C + h * Dh + d;
    float acc = 0.f;
    for (int l = 0; l < NLEV; l++) {
        float Wf = (float)cLW[l], Hf = (float)cLH[l];
        int Wi = cLW[l], Hi = cLH[l], S0 = cLS[l];
        for (int n = 0; n < NPTS; n++) {
            int oi = ((h * NLEV + l) * NPTS + n) * 2;
            float lx = sref[0] + soff[oi + 0] / Wf;
            float ly = sref[1] + soff[oi + 1] / Hf;
            float aww = sawL[(h * NLEV + l) * NPTS + n];
            float x = lx * Wf - 0.5f, y = ly * Hf - 0.5f;
            float x0f = floorf(x), y0f = floorf(y);
            float wx = x - x0f, wy = y - y0f;
            int x0 = (int)x0f, y0 = (int)y0f;
            float s = 0.f;
            #pragma unroll
            for (int dy = 0; dy < 2; dy++) {
                #pragma unroll
                for (int dx = 0; dx < 2; dx++) {
                    int xi = x0 + dx, yi = y0 + dy;
                    if (xi >= 0 && xi < Wi && yi >= 0 && yi < Hi) {
                        float wwt = (dx ? wx : 1.f - wx) * (dy ? wy : 1.f - wy);
                        s += wwt * tof(vbase[(size_t)(S0 + yi * Wi + xi) * C]);
                    }
                }
            }
            acc += aww * s;
        }
    }
    wsmut[OUTSo + (size_t)row * C + j] = acc;
}

// ---------------- FFN stage 1: x2 @ w1 + b1, relu -> hidb (bf16) ----------------
__global__ __launch_bounds__(256) void k_ffn1(const bf16* __restrict__ w1T, const float* __restrict__ b1,
                                              float* ws, bf16* hidb) {
    __shared__ __align__(16) bf16 As[32 * GAST];
    __shared__ __align__(16) bf16 Hs[32 * AST2];
    int row0 = blockIdx.x * 32;
    int nb = blockIdx.y * 512;
    int t = threadIdx.x;
    for (int rr = 0; rr < 32; rr++)
        As[rr * GAST + t] = tobf(ws[X2o + (size_t)(row0 + rr) * C + t]);
    __syncthreads();
    int wave = t >> 6, lane = t & 63, quad = lane >> 4, l15 = lane & 15;
    int n0 = wave * 128;
    floatx4 acc[2][8];
    #pragma unroll
    for (int i = 0; i < 2; i++)
        #pragma unroll
        for (int nt = 0; nt < 8; nt++) acc[i][nt] = (floatx4){0.f, 0.f, 0.f, 0.f};
    for (int kk = 0; kk < 8; kk++) {
        short8 a0 = *(const short8*)&As[l15 * GAST + kk * 32 + quad * 8];
        short8 a1 = *(const short8*)&As[(16 + l15) * GAST + kk * 32 + quad * 8];
        #pragma unroll
        for (int nt = 0; nt < 8; nt++) {
            short8 bf = *(const short8*)&w1T[(size_t)(nb + n0 + nt * 16 + l15) * 256 + kk * 32 + quad * 8];
            acc[0][nt] = __builtin_amdgcn_mfma_f32_16x16x32_bf16(a0, bf, acc[0][nt], 0, 0, 0);
            acc[1][nt] = __builtin_amdgcn_mfma_f32_16x16x32_bf16(a1, bf, acc[1][nt], 0, 0, 0);
        }
    }
    #pragma unroll
    for (int i = 0; i < 2; i++)
        #pragma unroll
        for (int nt = 0; nt < 8; nt++) {
            int cl = n0 + nt * 16 + l15;
            float bias = b1[nb + cl];
            int rl = i * 16 + quad * 4;
            #pragma unroll
            for (int u = 0; u < 4; u++)
                Hs[(rl + u) * AST2 + cl] = tobf(fmaxf(acc[i][nt][u] + bias, 0.f));
        }
    __syncthreads();
    #pragma unroll
    for (int pass = 0; pass < 8; pass++) {
        int row = pass * 4 + (t >> 6);
        int col = (t & 63) * 8;
        *(int4*)&hidb[(size_t)(row0 + row) * FFN + nb + col] = *(const int4*)&Hs[row * AST2 + col];
    }
}

// ---------------- FFN stage 2: hidb @ w2 + b2 + x2, LN -> x3 ----------------
__global__ __launch_bounds__(256) void k_ffn2(const bf16* __restrict__ w2T, const float* __restrict__ b2,
                                              const bf16* __restrict__ hidb, float* ws) {
    __shared__ __align__(16) float Os[32 * OST];
    __shared__ float redw[4][8][2];
    __shared__ float mv[8][2];
    int row0 = blockIdx.x * 32;
    int t = threadIdx.x;
    int wave = t >> 6, lane = t & 63, quad = lane >> 4, l15 = lane & 15;
    int n0 = wave * 64;
    floatx4 acc[2][4];
    #pragma unroll
    for (int i = 0; i < 2; i++)
        #pragma unroll
        for (int nt = 0; nt < 4; nt++) acc[i][nt] = (floatx4){0.f, 0.f, 0.f, 0.f};
    for (int kk = 0; kk < 32; kk++) {
        short8 a0 = *(const short8*)&hidb[(size_t)(row0 + l15) * FFN + kk * 32 + quad * 8];
        short8 a1 = *(const short8*)&hidb[(size_t)(row0 + 16 + l15) * FFN + kk * 32 + quad * 8];
        #pragma unroll
        for (int nt = 0; nt < 4; nt++) {
            short8 bf = *(const short8*)&w2T[(size_t)(n0 + nt * 16 + l15) * FFN + kk * 32 + quad * 8];
            acc[0][nt] = __builtin_amdgcn_mfma_f32_16x16x32_bf16(a0, bf, acc[0][nt], 0, 0, 0);
            acc[1][nt] = __builtin_amdgcn_mfma_f32_16x16x32_bf16(a1, bf, acc[1][nt], 0, 0, 0);
        }
    }
    #pragma unroll
    for (int i = 0; i < 2; i++)
        #pragma unroll
        for (int nt = 0; nt < 4; nt++) {
            int col = n0 + nt * 16 + l15;
            float bias = b2[col];
            int rl = i * 16 + quad * 4;
            #pragma unroll
            for (int u = 0; u < 4; u++) Os[(rl + u) * OST + col] = acc[i][nt][u] + bias;
        }
    __syncthreads();
    for (int g = 0; g < 4; g++) {
        float rv[8];
        #pragma unroll
        for (int r = 0; r < 8; r++) {
            int grow = row0 + g * 8 + r;
            rv[r] = Os[(g * 8 + r) * OST + t] + ws[X2o + (size_t)grow * C + t];
        }
        #pragma unroll
        for (int r = 0; r < 8; r++) {
            float s = rv[r], q = rv[r] * rv[r];
            for (int off = 32; off > 0; off >>= 1) {
                s += __shfl_down(s, off, 64);
                q += __shfl_down(q, off, 64);
            }
            if (lane == 0) { redw[wave][r][0] = s; redw[wave][r][1] = q; }
        }
        __syncthreads();
        if (t < 8) {
            float s = redw[0][t][0] + redw[1][t][0] + redw[2][t][0] + redw[3][t][0];
            float q = redw[0][t][1] + redw[1][t][1] + redw[2][t][1] + redw[3][t][1];
            float mean = s * (1.f / C);
            float var = q * (1.f / C) - mean * mean;
            mv[t][0] = mean; mv[t][1] = rsqrtf(var + 1e-5f);
        }
        __syncthreads();
        #pragma unroll
        for (int r = 0; r < 8; r++) {
            int grow = row0 + g * 8 + r;
            ws[X3o + (size_t)grow * C + t] = (rv[r] - mv[r][0]) * mv[r][1];
        }
        __syncthreads();
    }
}

// ---------------- masked view-mean + output0 ----------------
__global__ __launch_bounds__(256) void k_fuse(const int* maskin, float* ws, float* out) {
    int row = blockIdx.x, j = threadIdx.x;
    int b = row / P, p = row % P;
    float s = 0.f, cnt = 0.f;
    for (int v = 0; v < V; v++) {
        bool mk = (maskin[(b * P + p) * V + v] > 0) && (ws[MFLAG + b * V + v] > 0.5f);
        if (mk) {
            s += ws[X3o + ((size_t)((b * V + v) * P + p)) * C + j];
            cnt += 1.f;
        }
    }
    float f = s / (cnt + 1e-4f);
    ws[FUSEDo + (size_t)row * C + j] = f;
    out[O0 + ((size_t)b * C + j) * P + p] = f;
}

// ---------------- pred head + BEV outputs ----------------
__global__ __launch_bounds__(256) void k_pred(const float* w1, const float* b1, const float* w2, const float* b2,
                                              const float* qposin, float* ws, float* out) {
    int row = blockIdx.x, j = threadIdx.x;
    __shared__ __align__(16) float in[C];
    __shared__ float red[256];
    __shared__ float cen[4];
    in[j] = ws[FUSEDo + (size_t)row * C + j];
    __syncthreads();
    float h = fmaxf(b1[j] + dotK(in, w1, j, C, C), 0.f);
    for (int i = 0; i < 3; i++) {
        float s = blockReduceSum(h * w2[j * 3 + i], red);
        if (j == 0) cen[i] = s + b2[i] + qposin[row * 3 + i];
    }
    if (j == 0) {
        float c0 = cen[0], c1 = cen[1], c2 = cen[2];
        float cx = (c0 + 54.f) / 108.f * 135.f;
        float cy = (c1 + 54.f) / 108.f * 135.f;
        int b = row / P, p = row % P;
        out[O1 + (size_t)row * 3 + 0] = c0;
        out[O1 + (size_t)row * 3 + 1] = c1;
        out[O1 + (size_t)row * 3 + 2] = c2;
        out[O2 + (size_t)row * 2 + 0] = cx;
        out[O2 + (size_t)row * 2 + 1] = cy;
        out[O3 + (size_t)b * 2 * P + 0 * P + p] = cx;
        out[O3 + (size_t)b * 2 * P + 1 * P + p] = cy;
        out[O4 + (size_t)b * P + p] = c2;
    }
}

extern "C" void kernel_launch(void* const* d_in, const int* in_sizes, int n_in,
                              void* d_out, int out_size, void* d_ws, size_t ws_size,
                              hipStream_t stream) {
    const float* qfeat  = (const float*)d_in[0];
    const float* qposin = (const float*)d_in[1];
    const int*   maskin = (const int*)d_in[2];
    const float* feats  = (const float*)d_in[3];
    const float* npos   = (const float*)d_in[4];
    const float* rt     = (const float*)d_in[5];
    const float* l2cr   = (const float*)d_in[6];
    const float* l2ct   = (const float*)d_in[7];
    const float* qp_w1 = (const float*)d_in[8],  * qp_b1 = (const float*)d_in[9];
    const float* qp_w2 = (const float*)d_in[10], * qp_b2 = (const float*)d_in[11];
    const float* kp_w1 = (const float*)d_in[12], * kp_b1 = (const float*)d_in[13];
    const float* kp_w2 = (const float*)d_in[14], * kp_b2 = (const float*)d_in[15];
    const float* sa_wq = (const float*)d_in[16], * sa_wk = (const float*)d_in[17];
    const float* sa_wv = (const float*)d_in[18];
    const float* sa_wo = (const float*)d_in[19];
    const float* dv_w  = (const float*)d_in[20];
    const float* doffw = (const float*)d_in[21], * doffb = (const float*)d_in[22];
    const float* dattw = (const float*)d_in[23], * dattb = (const float*)d_in[24];
    const float* doutw = (const float*)d_in[25];
    const float* f_w1  = (const float*)d_in[26], * f_b1 = (const float*)d_in[27];
    const float* f_w2  = (const float*)d_in[28], * f_b2 = (const float*)d_in[29];
    const float* p_w1  = (const float*)d_in[30], * p_b1 = (const float*)d_in[31];
    const float* p_w2  = (const float*)d_in[32], * p_b2 = (const float*)d_in[33];

    float* ws = (float*)d_ws;
    bf16* vals = (bf16*)((char*)d_ws + VALS_BYTE_OFF);
    bf16* wb = vals + VALS_ELEMS;
    bf16* hidb = wb + HIDB_O;
    float* out = (float*)d_out;

    k_setup<<<1, 64, 0, stream>>>(rt, l2cr, l2ct, maskin, ws);
    k_wprep_all<<<3456, 256, 0, stream>>>(kp_w2, dv_w, sa_wo, doutw, doffw, dattw,
                                          sa_wq, sa_wk, sa_wv, f_w1, f_w2, wb);
    k_wfuse<<<8, 256, 0, stream>>>(wb + DVWT_O, wb + KW2NB_O, kp_b2, wb + KDVT_O, ws);
    k_qpos<<<BP, 256, 0, stream>>>(qfeat, qposin, qp_w1, qp_b1, qp_w2, qp_b2, ws);
    k_qkv_mfma<<<BP / 16, 256, 0, stream>>>(wb + QKVT_O, ws);
    k_logits<<<B * HH * P, 256, 0, stream>>>(ws);
    k_sattn<<<B * HH * P, 256, 0, stream>>>(maskin, ws);
    k_lngemm<<<BVP / 32, 256, 0, stream>>>(wb + WOT_O, ws, SAo, Xo, 1, X1o);
    k_ref<<<(BVP + 255) / 256, 256, 0, stream>>>(qposin, rt, ws);
    k_offaw_mfma<<<BVP / 32, 256, 0, stream>>>(wb + OAWT_O, doffb, dattb, ws);
    k_vals_mfma<<<dim3(NVT, BV), 256, 0, stream>>>(npos, feats, kp_w1, kp_b1,
                                                   wb + KDVT_O, wb + DVWT_O, ws, vals);
    k_sample<<<BVP, 256, 0, stream>>>(ws, vals, ws);
    k_lngemm<<<BVP / 32, 256, 0, stream>>>(wb + DOUTT_O, ws, OUTSo, X1o, 0, X2o);
    k_ffn1<<<dim3(BVP / 32, 2), 256, 0, stream>>>(wb + W1T_O, f_b1, ws, hidb);
    k_ffn2<<<BVP / 32, 256, 0, stream>>>(wb + W2T_O, f_b2, hidb, ws);
    k_fuse<<<BP, 256, 0, stream>>>(maskin, ws, out);
    k_pred<<<BP, 256, 0, stream>>>(p_w1, p_b1, p_w2, p_b2, qposin, ws, out);
}